// Round 1
// baseline (1582.509 us; speedup 1.0000x reference)
//
#include <hip/hip_runtime.h>
#include <math.h>

// Problem constants
constexpr int Dm   = 1024;   // model dim (D_IN == D_OUT)
constexpr int NH   = 16;     // heads
constexpr int HD   = 64;     // head dim
constexpr int Bb   = 2;      // batch
constexpr int Tt   = 2048;   // seq len
constexpr int MTOT = Bb * Tt;  // 4096 rows
#define EPSF 1e-6f
#define INV_PI 0.31830988618379067f

// ---------------------------------------------------------------------------
// C[M,N] = A[M,K] @ W[N,K]^T (+ bias[N] if bias != nullptr)
// 64x64 tile, BK=16, 256 threads, 4x4 per thread. fp32.
// ---------------------------------------------------------------------------
__global__ __launch_bounds__(256)
void gemm_nt(const float* __restrict__ A, const float* __restrict__ Wt,
             const float* __restrict__ bias, float* __restrict__ C,
             int M, int N, int K) {
    __shared__ float As[64][17];
    __shared__ float Ws[64][17];
    const int tid = threadIdx.x;
    const int tx = tid & 15, ty = tid >> 4;
    const int m0 = blockIdx.x * 64, n0 = blockIdx.y * 64;
    const int lr = tid >> 4;   // 0..15
    const int lc = tid & 15;   // 0..15 (k within tile)

    float acc[4][4] = {};
    for (int k0 = 0; k0 < K; k0 += 16) {
        #pragma unroll
        for (int i = 0; i < 4; i++) {
            As[lr + 16 * i][lc] = A[(size_t)(m0 + lr + 16 * i) * K + k0 + lc];
            Ws[lr + 16 * i][lc] = Wt[(size_t)(n0 + lr + 16 * i) * K + k0 + lc];
        }
        __syncthreads();
        #pragma unroll
        for (int kk = 0; kk < 16; kk++) {
            float a[4], w[4];
            #pragma unroll
            for (int i = 0; i < 4; i++) a[i] = As[4 * ty + i][kk];
            #pragma unroll
            for (int j = 0; j < 4; j++) w[j] = Ws[4 * tx + j][kk];
            #pragma unroll
            for (int i = 0; i < 4; i++)
                #pragma unroll
                for (int j = 0; j < 4; j++)
                    acc[i][j] = fmaf(a[i], w[j], acc[i][j]);
        }
        __syncthreads();
    }
    #pragma unroll
    for (int i = 0; i < 4; i++) {
        const int m = m0 + 4 * ty + i;
        #pragma unroll
        for (int j = 0; j < 4; j++) {
            const int n = n0 + 4 * tx + j;
            float v = acc[i][j];
            if (bias) v += bias[n];
            C[(size_t)m * N + n] = v;
        }
    }
}

// ---------------------------------------------------------------------------
// L2-normalize contiguous 64-element rows (one wave per row), for q then k.
// rows_per = MTOT*NH per tensor. Matches torch F.normalize: t / max(||t||, eps)
// ---------------------------------------------------------------------------
__global__ __launch_bounds__(256)
void l2norm64(float* __restrict__ qa, float* __restrict__ ka, int rows_per) {
    const int widx = (int)((blockIdx.x * (size_t)blockDim.x + threadIdx.x) >> 6);
    const int lane = threadIdx.x & 63;
    float* p = (widx < rows_per) ? qa : ka;
    int row = (widx < rows_per) ? widx : widx - rows_per;
    if (row >= rows_per) return;
    const size_t off = (size_t)row * 64 + lane;
    const float v = p[off];
    float s = v * v;
    #pragma unroll
    for (int o = 32; o > 0; o >>= 1) s += __shfl_xor(s, o, 64);
    p[off] = v / fmaxf(sqrtf(s), EPSF);
}

// ---------------------------------------------------------------------------
// Fused angular attention (flash-style streaming; weights positive so no
// max-rescaling needed). One block = (b, h, 64-query tile). fp32.
//   S = Q K^T  (Q,K already L2-normalized)
//   w = max(1 - acos(clip(S,-.999,.999))/pi, eps)^16
//   O = (sum_s w*V) / (sum_s w + eps)
// ---------------------------------------------------------------------------
__global__ __launch_bounds__(256)
void angular_attn(const float* __restrict__ Q, const float* __restrict__ Kt,
                  const float* __restrict__ V, float* __restrict__ O) {
    __shared__ float Ql[64][65];
    __shared__ float Kl[64][65];
    __shared__ float Vl[64][65];
    __shared__ float Wl[64][65];
    __shared__ float den[64];

    const int tid = threadIdx.x;
    const int tx = tid & 15, ty = tid >> 4;
    const int t0 = blockIdx.x * 64;
    const int h  = blockIdx.y;
    const int b  = blockIdx.z;
    const size_t rowbase = (size_t)(b * Tt) * Dm + (size_t)h * HD;

    // load Q tile (64 queries x 64 dims); coalesced 64-float rows
    #pragma unroll
    for (int i = 0; i < 16; i++) {
        const int idx = tid + 256 * i;
        const int r = idx >> 6, c = idx & 63;
        Ql[r][c] = Q[rowbase + (size_t)(t0 + r) * Dm + c];
    }
    if (tid < 64) den[tid] = 0.f;
    float acc[4][4] = {};

    for (int s0 = 0; s0 < Tt; s0 += 64) {
        #pragma unroll
        for (int i = 0; i < 16; i++) {
            const int idx = tid + 256 * i;
            const int r = idx >> 6, c = idx & 63;
            Kl[r][c] = Kt[rowbase + (size_t)(s0 + r) * Dm + c];
            Vl[r][c] = V [rowbase + (size_t)(s0 + r) * Dm + c];
        }
        __syncthreads();   // covers Ql/den on first iteration too

        // S tile in registers: rows 4ty..+3, cols 4tx..+3
        float s[4][4] = {};
        #pragma unroll 8
        for (int d = 0; d < 64; d++) {
            float qv[4], kv[4];
            #pragma unroll
            for (int i = 0; i < 4; i++) qv[i] = Ql[4 * ty + i][d];
            #pragma unroll
            for (int j = 0; j < 4; j++) kv[j] = Kl[4 * tx + j][d];
            #pragma unroll
            for (int i = 0; i < 4; i++)
                #pragma unroll
                for (int j = 0; j < 4; j++)
                    s[i][j] = fmaf(qv[i], kv[j], s[i][j]);
        }
        // angular weight transform -> Wl
        #pragma unroll
        for (int i = 0; i < 4; i++)
            #pragma unroll
            for (int j = 0; j < 4; j++) {
                float c = fminf(fmaxf(s[i][j], -0.999f), 0.999f);
                float sc = 1.f - acosf(c) * INV_PI;
                sc = fmaxf(sc, EPSF);
                float p2 = sc * sc;
                float p4 = p2 * p2;
                float p8 = p4 * p4;
                Wl[4 * ty + i][4 * tx + j] = p8 * p8;
            }
        __syncthreads();

        // denominator accumulation (row sums of Wl)
        if (tid < 64) {
            float ds = 0.f;
            #pragma unroll 8
            for (int j2 = 0; j2 < 64; j2++) ds += Wl[tid][j2];
            den[tid] += ds;
        }
        // PV accumulate: acc[r][d] += sum_s Wl[r][s] * Vl[s][d]
        #pragma unroll 8
        for (int sI = 0; sI < 64; sI++) {
            float wv[4], vv[4];
            #pragma unroll
            for (int i = 0; i < 4; i++) wv[i] = Wl[4 * ty + i][sI];
            #pragma unroll
            for (int j = 0; j < 4; j++) vv[j] = Vl[sI][4 * tx + j];
            #pragma unroll
            for (int i = 0; i < 4; i++)
                #pragma unroll
                for (int j = 0; j < 4; j++)
                    acc[i][j] = fmaf(wv[i], vv[j], acc[i][j]);
        }
        __syncthreads();   // protect Kl/Vl/Wl before next tile load
    }

    #pragma unroll
    for (int i = 0; i < 4; i++) {
        const float inv = 1.f / (den[4 * ty + i] + EPSF);
        #pragma unroll
        for (int j = 0; j < 4; j++) {
            O[rowbase + (size_t)(t0 + 4 * ty + i) * Dm + 4 * tx + j] =
                acc[i][j] * inv;
        }
    }
}

// ---------------------------------------------------------------------------
extern "C" void kernel_launch(void* const* d_in, const int* in_sizes, int n_in,
                              void* d_out, int out_size, void* d_ws, size_t ws_size,
                              hipStream_t stream) {
    const float* x  = (const float*)d_in[0];
    const float* Wq = (const float*)d_in[1];
    const float* Wk = (const float*)d_in[2];
    const float* Wv = (const float*)d_in[3];
    const float* Wo = (const float*)d_in[4];
    const float* bo = (const float*)d_in[5];
    float* out = (float*)d_out;

    float* ws = (float*)d_ws;
    const size_t NBUF = (size_t)MTOT * Dm;   // 4 Mi floats each
    float* q  = ws;
    float* k  = ws + NBUF;
    float* v  = ws + 2 * NBUF;
    float* ao = ws + 3 * NBUF;

    const dim3 gblk(256);
    const dim3 ggrid(MTOT / 64, Dm / 64);    // 64 x 16

    // Q/K/V projections
    gemm_nt<<<ggrid, gblk, 0, stream>>>(x, Wq, nullptr, q, MTOT, Dm, Dm);
    gemm_nt<<<ggrid, gblk, 0, stream>>>(x, Wk, nullptr, k, MTOT, Dm, Dm);
    gemm_nt<<<ggrid, gblk, 0, stream>>>(x, Wv, nullptr, v, MTOT, Dm, Dm);

    // L2 normalize Q and K per (token, head) 64-vector
    const int rows_per = MTOT * NH;          // 65536
    const int nwaves   = 2 * rows_per;
    l2norm64<<<dim3(nwaves / 4), gblk, 0, stream>>>(q, k, rows_per);

    // fused attention
    angular_attn<<<dim3(Tt / 64, NH, Bb), gblk, 0, stream>>>(q, k, v, ao);

    // output projection + bias
    gemm_nt<<<ggrid, gblk, 0, stream>>>(ao, Wo, bo, out, MTOT, Dm, Dm);
}

// Round 2
// 333.939 us; speedup vs baseline: 4.7389x; 4.7389x over previous
//
#include <hip/hip_runtime.h>
#include <math.h>

// Problem constants
constexpr int Dm   = 1024;
constexpr int NH   = 16;
constexpr int HD   = 64;
constexpr int Bb   = 2;
constexpr int Tt   = 2048;
constexpr int MTOT = Bb * Tt;   // 4096
#define EPSF 1e-6f
#define INV_PI 0.31830988618379067f

typedef __attribute__((ext_vector_type(8))) short short8;   // 8 x bf16 (4 VGPRs)
typedef __attribute__((ext_vector_type(4))) float f32x4;    // MFMA accumulator

__device__ __forceinline__ ushort f2bf(float f) {
    union { float f; unsigned u; } v; v.f = f;
    unsigned r = (v.u + 0x7FFFu + ((v.u >> 16) & 1u)) >> 16;   // RNE
    return (ushort)r;
}
__device__ __forceinline__ float bf2f(ushort b) {
    union { unsigned u; float f; } v; v.u = ((unsigned)b) << 16;
    return v.f;
}

// ---------------------------------------------------------------------------
// fp32 -> bf16 convert (vectorized float4 -> ushort4)
// ---------------------------------------------------------------------------
__global__ __launch_bounds__(256)
void cvt_bf16(const float* __restrict__ in, ushort* __restrict__ out, int n4) {
    const int i = blockIdx.x * 256 + threadIdx.x;
    if (i >= n4) return;
    const float4 v = ((const float4*)in)[i];
    ushort4 o;
    o.x = f2bf(v.x); o.y = f2bf(v.y); o.z = f2bf(v.z); o.w = f2bf(v.w);
    ((ushort4*)out)[i] = o;
}

// ---------------------------------------------------------------------------
// In-place L2 normalize of contiguous 64-elem bf16 rows, for qb then kb.
// One wave handles 4 rows: lane covers row (lane>>4), elems (lane&15)*4.
// 16384 waves per tensor -> 32768 waves total -> 8192 blocks.
// ---------------------------------------------------------------------------
__global__ __launch_bounds__(256)
void l2norm4(ushort* __restrict__ qb, ushort* __restrict__ kb) {
    const int gwave = (blockIdx.x * 256 + threadIdx.x) >> 6;
    const int lane  = threadIdx.x & 63;
    ushort* p = (gwave < 16384) ? qb : kb;
    const int w = gwave & 16383;
    const size_t off = (size_t)w * 256 + (size_t)(lane >> 4) * 64 + (lane & 15) * 4;
    ushort4 uv = *(ushort4*)&p[off];
    float f0 = bf2f(uv.x), f1 = bf2f(uv.y), f2 = bf2f(uv.z), f3 = bf2f(uv.w);
    float s = f0*f0 + f1*f1 + f2*f2 + f3*f3;
    s += __shfl_xor(s, 1); s += __shfl_xor(s, 2);
    s += __shfl_xor(s, 4); s += __shfl_xor(s, 8);
    const float inv = 1.f / fmaxf(sqrtf(s), EPSF);
    uv.x = f2bf(f0 * inv); uv.y = f2bf(f1 * inv);
    uv.z = f2bf(f2 * inv); uv.w = f2bf(f3 * inv);
    *(ushort4*)&p[off] = uv;
}

// ---------------------------------------------------------------------------
// V [b,t,h*64+d] bf16  ->  Vt [b,h,d,t] bf16  (per-head transpose)
// ---------------------------------------------------------------------------
__global__ __launch_bounds__(256)
void vtranspose(const ushort* __restrict__ vb, ushort* __restrict__ vtb) {
    __shared__ ushort T[64][72];
    const int tid = threadIdx.x;
    const int s0 = blockIdx.x * 64, h = blockIdx.y, b = blockIdx.z;
    const size_t vtbase = (size_t)((b * NH + h) * HD) * Tt;
    for (int c = tid; c < 512; c += 256) {
        const int s = c >> 3, d0 = (c & 7) * 8;
        *(short8*)&T[s][d0] =
            *(const short8*)&vb[(size_t)(b * Tt + s0 + s) * Dm + h * HD + d0];
    }
    __syncthreads();
    for (int c = tid; c < 512; c += 256) {
        const int d = c >> 3, sc = (c & 7) * 8;
        short8 val;
        #pragma unroll
        for (int i = 0; i < 8; i++) val[i] = (short)T[sc + i][d];
        *(short8*)&vtb[vtbase + (size_t)d * Tt + s0 + sc] = val;
    }
}

// ---------------------------------------------------------------------------
// C[M,N] = A[M,K](bf16) @ W[N,K](bf16)^T ; out bf16 or fp32(+bias)
// 64x64 tile, BK=64, 4 waves, mfma_f32_16x16x32_bf16. LDS pitch 72 (pad).
// ---------------------------------------------------------------------------
template<bool OUT_F32>
__global__ __launch_bounds__(256)
void gemm_bf16(const ushort* __restrict__ A, const ushort* __restrict__ W,
               const float* __restrict__ bias, void* __restrict__ Cout,
               int M, int N, int K) {
    __shared__ ushort As[64][72];
    __shared__ ushort Bs[64][72];
    const int tid  = threadIdx.x;
    const int wave = tid >> 6, lane = tid & 63;
    const int quad = lane >> 4, l15 = lane & 15;
    const int m0 = blockIdx.x * 64, n0 = blockIdx.y * 64;

    f32x4 acc[4] = {};
    for (int k0 = 0; k0 < K; k0 += 64) {
        for (int c = tid; c < 512; c += 256) {
            const int r = c >> 3, cc = (c & 7) * 8;
            *(short8*)&As[r][cc] = *(const short8*)&A[(size_t)(m0 + r) * K + k0 + cc];
            *(short8*)&Bs[r][cc] = *(const short8*)&W[(size_t)(n0 + r) * K + k0 + cc];
        }
        __syncthreads();
        const short8 af0 = *(const short8*)&As[16 * wave + l15][quad * 8];
        const short8 af1 = *(const short8*)&As[16 * wave + l15][32 + quad * 8];
        #pragma unroll
        for (int j = 0; j < 4; j++) {
            const short8 bf0 = *(const short8*)&Bs[16 * j + l15][quad * 8];
            const short8 bf1 = *(const short8*)&Bs[16 * j + l15][32 + quad * 8];
            acc[j] = __builtin_amdgcn_mfma_f32_16x16x32_bf16(af0, bf0, acc[j], 0, 0, 0);
            acc[j] = __builtin_amdgcn_mfma_f32_16x16x32_bf16(af1, bf1, acc[j], 0, 0, 0);
        }
        __syncthreads();
    }
    // epilogue: C row = 16*wave + quad*4 + r, col = 16*j + l15
    #pragma unroll
    for (int j = 0; j < 4; j++)
        #pragma unroll
        for (int r = 0; r < 4; r++) {
            const int m = m0 + 16 * wave + quad * 4 + r;
            const int n = n0 + 16 * j + l15;
            if (OUT_F32)
                ((float*)Cout)[(size_t)m * N + n] = acc[j][r] + bias[n];
            else
                ((ushort*)Cout)[(size_t)m * N + n] = f2bf(acc[j][r]);
        }
}

// ---------------------------------------------------------------------------
// Fused angular attention, bf16 MFMA.
// Block = (64-q-tile, h, b); 4 waves x 16 q-rows. Q frags in registers.
// S (C-layout) -> angular transform in-register -> Ws LDS (A-layout) -> PV.
// Denominator: per-lane partials, one 16-lane butterfly at the end.
// ---------------------------------------------------------------------------
__global__ __launch_bounds__(256)
void attn_kernel(const ushort* __restrict__ Qb, const ushort* __restrict__ Kb,
                 const ushort* __restrict__ Vtb, ushort* __restrict__ Ob) {
    __shared__ ushort Ks[64][72];
    __shared__ ushort Vs[64][72];   // V^T tile: rows d, cols s
    __shared__ ushort Ws[64][72];   // weight tile: rows q, cols s
    const int tid  = threadIdx.x;
    const int wave = tid >> 6, lane = tid & 63;
    const int quad = lane >> 4, l15 = lane & 15;
    const int t0 = blockIdx.x * 64, h = blockIdx.y, b = blockIdx.z;

    // Q A-fragments for this wave's 16 rows (resident all kernel)
    const size_t qrow = (size_t)(b * Tt + t0 + 16 * wave + l15) * Dm + h * HD;
    const short8 qf0 = *(const short8*)&Qb[qrow + quad * 8];
    const short8 qf1 = *(const short8*)&Qb[qrow + 32 + quad * 8];

    f32x4 oacc[4] = {};
    float den[4] = {0.f, 0.f, 0.f, 0.f};
    const size_t kbase  = (size_t)(b * Tt) * Dm + h * HD;
    const size_t vtbase = (size_t)((b * NH + h) * HD) * Tt;

    for (int s0 = 0; s0 < Tt; s0 += 64) {
        for (int c = tid; c < 512; c += 256) {
            const int r = c >> 3, cc = (c & 7) * 8;
            *(short8*)&Ks[r][cc] = *(const short8*)&Kb[kbase + (size_t)(s0 + r) * Dm + cc];
            *(short8*)&Vs[r][cc] = *(const short8*)&Vtb[vtbase + (size_t)r * Tt + s0 + cc];
        }
        __syncthreads();

        // S = Q K^T : 4 s-subtiles of 16, K-dim 64 in two mfma
        f32x4 sf[4] = {};
        #pragma unroll
        for (int j = 0; j < 4; j++) {
            const short8 kf0 = *(const short8*)&Ks[16 * j + l15][quad * 8];
            const short8 kf1 = *(const short8*)&Ks[16 * j + l15][32 + quad * 8];
            sf[j] = __builtin_amdgcn_mfma_f32_16x16x32_bf16(qf0, kf0, sf[j], 0, 0, 0);
            sf[j] = __builtin_amdgcn_mfma_f32_16x16x32_bf16(qf1, kf1, sf[j], 0, 0, 0);
        }
        // angular transform; write A-layout weight tile
        #pragma unroll
        for (int j = 0; j < 4; j++)
            #pragma unroll
            for (int r = 0; r < 4; r++) {
                float c = fminf(fmaxf(sf[j][r], -0.999f), 0.999f);
                float sc = fmaxf(1.f - acosf(c) * INV_PI, EPSF);
                float p2 = sc * sc, p4 = p2 * p2, p8 = p4 * p4, w = p8 * p8;
                den[r] += w;
                Ws[16 * wave + quad * 4 + r][16 * j + l15] = f2bf(w);
            }
        __syncthreads();

        // O += W V : A-frags from Ws (own wave rows), B-frags from Vs
        const short8 wf0 = *(const short8*)&Ws[16 * wave + l15][quad * 8];
        const short8 wf1 = *(const short8*)&Ws[16 * wave + l15][32 + quad * 8];
        #pragma unroll
        for (int j = 0; j < 4; j++) {
            const short8 vf0 = *(const short8*)&Vs[16 * j + l15][quad * 8];
            const short8 vf1 = *(const short8*)&Vs[16 * j + l15][32 + quad * 8];
            oacc[j] = __builtin_amdgcn_mfma_f32_16x16x32_bf16(wf0, vf0, oacc[j], 0, 0, 0);
            oacc[j] = __builtin_amdgcn_mfma_f32_16x16x32_bf16(wf1, vf1, oacc[j], 0, 0, 0);
        }
        __syncthreads();   // protect Ks/Vs/Ws before next stage
    }

    // row-sum butterfly over the 16 lanes of each quad (den rows == oacc rows)
    #pragma unroll
    for (int r = 0; r < 4; r++) {
        float d = den[r];
        d += __shfl_xor(d, 1); d += __shfl_xor(d, 2);
        d += __shfl_xor(d, 4); d += __shfl_xor(d, 8);
        den[r] = d;
    }
    const size_t obase = (size_t)(b * Tt + t0 + 16 * wave + quad * 4) * Dm + h * HD + l15;
    #pragma unroll
    for (int j = 0; j < 4; j++)
        #pragma unroll
        for (int r = 0; r < 4; r++)
            Ob[obase + (size_t)r * Dm + 16 * j] = f2bf(oacc[j][r] / (den[r] + EPSF));
}

// ---------------------------------------------------------------------------
extern "C" void kernel_launch(void* const* d_in, const int* in_sizes, int n_in,
                              void* d_out, int out_size, void* d_ws, size_t ws_size,
                              hipStream_t stream) {
    const float* x  = (const float*)d_in[0];
    const float* Wq = (const float*)d_in[1];
    const float* Wk = (const float*)d_in[2];
    const float* Wv = (const float*)d_in[3];
    const float* Wo = (const float*)d_in[4];
    const float* bo = (const float*)d_in[5];
    float* out = (float*)d_out;

    ushort* ws = (ushort*)d_ws;
    const size_t M1 = 1u << 20;                 // 1Mi elems
    ushort* xb  = ws;                           // 4M elems (8MB)
    ushort* wqb = ws + 4 * M1;                  // 1M each
    ushort* wkb = ws + 5 * M1;
    ushort* wvb = ws + 6 * M1;
    ushort* wob = ws + 7 * M1;
    ushort* qb  = ws + 8 * M1;                  // 4M each
    ushort* kb  = ws + 12 * M1;
    ushort* vb  = ws + 16 * M1;
    ushort* vtb = ws + 20 * M1;
    ushort* aob = ws + 24 * M1;                 // total 28M elems = 56MB

    // fp32 -> bf16
    cvt_bf16<<<4096, 256, 0, stream>>>(x,  xb,  (MTOT * Dm) / 4);
    cvt_bf16<<<1024, 256, 0, stream>>>(Wq, wqb, (Dm * Dm) / 4);
    cvt_bf16<<<1024, 256, 0, stream>>>(Wk, wkb, (Dm * Dm) / 4);
    cvt_bf16<<<1024, 256, 0, stream>>>(Wv, wvb, (Dm * Dm) / 4);
    cvt_bf16<<<1024, 256, 0, stream>>>(Wo, wob, (Dm * Dm) / 4);

    // projections (bf16 out)
    const dim3 ggrid(MTOT / 64, Dm / 64);
    gemm_bf16<false><<<ggrid, 256, 0, stream>>>(xb, wqb, nullptr, qb, MTOT, Dm, Dm);
    gemm_bf16<false><<<ggrid, 256, 0, stream>>>(xb, wkb, nullptr, kb, MTOT, Dm, Dm);
    gemm_bf16<false><<<ggrid, 256, 0, stream>>>(xb, wvb, nullptr, vb, MTOT, Dm, Dm);

    // L2 normalize q,k in place; build V^T
    l2norm4<<<8192, 256, 0, stream>>>(qb, kb);
    vtranspose<<<dim3(Tt / 64, NH, Bb), 256, 0, stream>>>(vb, vtb);

    // fused attention (bf16 out)
    attn_kernel<<<dim3(Tt / 64, NH, Bb), 256, 0, stream>>>(qb, kb, vtb, aob);

    // output projection (fp32 out + bias)
    gemm_bf16<true><<<ggrid, 256, 0, stream>>>(aob, wob, bo, (void*)out, MTOT, Dm, Dm);
}

// Round 3
// 298.453 us; speedup vs baseline: 5.3024x; 1.1189x over previous
//
#include <hip/hip_runtime.h>
#include <math.h>

// Problem constants
constexpr int Dm   = 1024;
constexpr int NH   = 16;
constexpr int HD   = 64;
constexpr int Bb   = 2;
constexpr int Tt   = 2048;
constexpr int MTOT = Bb * Tt;   // 4096
#define EPSF 1e-6f
#define INV_PI 0.31830988618379067f

typedef __attribute__((ext_vector_type(8))) short short8;   // 8 x bf16 (4 VGPRs)
typedef __attribute__((ext_vector_type(4))) float f32x4;    // MFMA accumulator

__device__ __forceinline__ ushort f2bf(float f) {
    union { float f; unsigned u; } v; v.f = f;
    unsigned r = (v.u + 0x7FFFu + ((v.u >> 16) & 1u)) >> 16;   // RNE
    return (ushort)r;
}
__device__ __forceinline__ float bf2f(ushort b) {
    union { unsigned u; float f; } v; v.u = ((unsigned)b) << 16;
    return v.f;
}

// async global->LDS, 16B per lane. LDS dest is wave-uniform base; lane i
// deposits at base + i*16 (m104/m108 semantics).
__device__ __forceinline__ void gload16(const void* g, void* l) {
    __builtin_amdgcn_global_load_lds(
        (const __attribute__((address_space(1))) unsigned int*)g,
        (__attribute__((address_space(3))) unsigned int*)l,
        16, 0, 0);
}

// ---------------------------------------------------------------------------
// fp32 -> bf16 for all five tensors in one launch (2M float4 groups).
// segments: x 1M | Wq 256K | Wk 256K | Wv 256K | Wo 256K
// ---------------------------------------------------------------------------
__global__ __launch_bounds__(256)
void cvt_all(const float* __restrict__ x,  const float* __restrict__ wq,
             const float* __restrict__ wk, const float* __restrict__ wv,
             const float* __restrict__ wo,
             ushort* __restrict__ xb,  ushort* __restrict__ wqb,
             ushort* __restrict__ wkb, ushort* __restrict__ wvb,
             ushort* __restrict__ wob) {
    int i = blockIdx.x * 256 + threadIdx.x;   // float4 index
    const float* src; ushort* dst; int off;
    if (i < 1048576)      { src = x;  dst = xb;  off = i; }
    else if (i < 1310720) { src = wq; dst = wqb; off = i - 1048576; }
    else if (i < 1572864) { src = wk; dst = wkb; off = i - 1310720; }
    else if (i < 1835008) { src = wv; dst = wvb; off = i - 1572864; }
    else                  { src = wo; dst = wob; off = i - 1835008; }
    const float4 v = ((const float4*)src)[off];
    ushort4 o;
    o.x = f2bf(v.x); o.y = f2bf(v.y); o.z = f2bf(v.z); o.w = f2bf(v.w);
    ((ushort4*)dst)[off] = o;
}

// ---------------------------------------------------------------------------
// 128x128x(BK=64) bf16 MFMA GEMM core (m97-style).
// C[M,N] = A[M,K] @ W[N,K]^T. 4 waves in 2x2; wave computes 64x64 (16 accs).
// LDS unpadded [128][64] with XOR chunk swizzle: LDS[r][c] = glob chunk c^(r&7)
// -> both global_load_lds (contiguous lane order) and b128 frag reads stay
//    conflict-free (2-way aliasing max, free per m136).
// Epilogue: do_norm -> per-row L2 norm over this wave's 64-col head (butterfly)
// ---------------------------------------------------------------------------
template<bool OUTF32>
__device__ __forceinline__
void gemm_core(const ushort* __restrict__ A, const ushort* __restrict__ W,
               const float* __restrict__ bias, void* __restrict__ out,
               int m0, int n0, int N, int K, bool do_norm) {
    __shared__ ushort As[128 * 64];
    __shared__ ushort Bs[128 * 64];
    const int tid  = threadIdx.x;
    const int wave = tid >> 6, lane = tid & 63;
    const int quad = lane >> 4, l15 = lane & 15;
    const int wr = wave >> 1, wc = wave & 1;
    const int lr = lane >> 3;            // 0..7 row within 8-row group
    const int sc = (lane & 7) ^ lr;      // swizzled global k-chunk for this lane

    f32x4 acc[4][4] = {};
    const ushort* Ab = A + (size_t)(m0 + lr) * K + sc * 8;
    const ushort* Wb = W + (size_t)(n0 + lr) * K + sc * 8;

    for (int k0 = 0; k0 < K; k0 += 64) {
        #pragma unroll
        for (int i = 0; i < 4; i++) {
            const int rows8 = (wave * 4 + i) * 8;          // wave-uniform
            gload16(Ab + (size_t)rows8 * K + k0, &As[rows8 * 64]);
            gload16(Wb + (size_t)rows8 * K + k0, &Bs[rows8 * 64]);
        }
        __syncthreads();   // drains vmcnt for the global_load_lds
        #pragma unroll
        for (int kh = 0; kh < 2; kh++) {
            short8 af[4];
            #pragma unroll
            for (int mi = 0; mi < 4; mi++) {
                const int row = wr * 64 + mi * 16 + l15;
                af[mi] = *(const short8*)&As[row * 64 + (((kh * 4 + quad) ^ (row & 7)) * 8)];
            }
            #pragma unroll
            for (int nj = 0; nj < 4; nj++) {
                const int row = wc * 64 + nj * 16 + l15;
                const short8 bf = *(const short8*)&Bs[row * 64 + (((kh * 4 + quad) ^ (row & 7)) * 8)];
                #pragma unroll
                for (int mi = 0; mi < 4; mi++)
                    acc[mi][nj] = __builtin_amdgcn_mfma_f32_16x16x32_bf16(af[mi], bf, acc[mi][nj], 0, 0, 0);
            }
        }
        __syncthreads();
    }

    // epilogue: row = m0+wr*64+mi*16+quad*4+r, col = n0+wc*64+nj*16+l15
    #pragma unroll
    for (int mi = 0; mi < 4; mi++) {
        float inv[4] = {1.f, 1.f, 1.f, 1.f};
        if (!OUTF32 && do_norm) {
            #pragma unroll
            for (int r = 0; r < 4; r++) {
                float ss = 0.f;
                #pragma unroll
                for (int nj = 0; nj < 4; nj++) ss += acc[mi][nj][r] * acc[mi][nj][r];
                ss += __shfl_xor(ss, 1); ss += __shfl_xor(ss, 2);
                ss += __shfl_xor(ss, 4); ss += __shfl_xor(ss, 8);
                inv[r] = 1.f / fmaxf(sqrtf(ss), EPSF);
            }
        }
        #pragma unroll
        for (int nj = 0; nj < 4; nj++)
            #pragma unroll
            for (int r = 0; r < 4; r++) {
                const int row = m0 + wr * 64 + mi * 16 + quad * 4 + r;
                const int col = n0 + wc * 64 + nj * 16 + l15;
                if (OUTF32)
                    ((float*)out)[(size_t)row * N + col] = acc[mi][nj][r] + bias[col];
                else
                    ((ushort*)out)[(size_t)row * N + col] = f2bf(acc[mi][nj][r] * inv[r]);
            }
    }
}

// Fused Q/K/V projection: grid (32, 24); y-tiles 0-7 -> Q(norm), 8-15 -> K(norm),
// 16-23 -> V(plain). Norm is valid because a wave's 64 cols == one full head.
__global__ __launch_bounds__(256)
void qkv_gemm(const ushort* __restrict__ xb,
              const ushort* __restrict__ wq, const ushort* __restrict__ wk,
              const ushort* __restrict__ wv,
              ushort* __restrict__ qb, ushort* __restrict__ kb,
              ushort* __restrict__ vb) {
    const int ny = blockIdx.y, sel = ny >> 3;
    const ushort* W = (sel == 0) ? wq : (sel == 1) ? wk : wv;
    ushort* out     = (sel == 0) ? qb : (sel == 1) ? kb : vb;
    gemm_core<false>(xb, W, nullptr, out, blockIdx.x * 128, (ny & 7) * 128,
                     Dm, Dm, sel < 2);
}

__global__ __launch_bounds__(256)
void out_gemm(const ushort* __restrict__ aob, const ushort* __restrict__ wob,
              const float* __restrict__ bias, float* __restrict__ out) {
    gemm_core<true>(aob, wob, bias, out, blockIdx.x * 128, blockIdx.y * 128,
                    Dm, Dm, false);
}

// ---------------------------------------------------------------------------
// V [b,t,h*64+d] bf16  ->  Vt [b,h,d,t] bf16  (per-head transpose)
// ---------------------------------------------------------------------------
__global__ __launch_bounds__(256)
void vtranspose(const ushort* __restrict__ vb, ushort* __restrict__ vtb) {
    __shared__ ushort T[64][72];
    const int tid = threadIdx.x;
    const int s0 = blockIdx.x * 64, h = blockIdx.y, b = blockIdx.z;
    const size_t vtbase = (size_t)((b * NH + h) * HD) * Tt;
    for (int c = tid; c < 512; c += 256) {
        const int s = c >> 3, d0 = (c & 7) * 8;
        *(short8*)&T[s][d0] =
            *(const short8*)&vb[(size_t)(b * Tt + s0 + s) * Dm + h * HD + d0];
    }
    __syncthreads();
    for (int c = tid; c < 512; c += 256) {
        const int d = c >> 3, scol = (c & 7) * 8;
        short8 val;
        #pragma unroll
        for (int i = 0; i < 8; i++) val[i] = (short)T[scol + i][d];
        *(short8*)&vtb[vtbase + (size_t)d * Tt + s0 + scol] = val;
    }
}

// ---------------------------------------------------------------------------
// Fused angular attention, bf16 MFMA + fast branchless acos.
// Block = (64-q-tile, h, b); 4 waves x 16 q-rows. Q frags in registers.
// ---------------------------------------------------------------------------
__global__ __launch_bounds__(256)
void attn_kernel(const ushort* __restrict__ Qb, const ushort* __restrict__ Kb,
                 const ushort* __restrict__ Vtb, ushort* __restrict__ Ob) {
    __shared__ ushort Ks[64][72];
    __shared__ ushort Vs[64][72];   // V^T tile: rows d, cols s
    __shared__ ushort Ws[64][72];   // weight tile: rows q, cols s
    const int tid  = threadIdx.x;
    const int wave = tid >> 6, lane = tid & 63;
    const int quad = lane >> 4, l15 = lane & 15;
    const int t0 = blockIdx.x * 64, h = blockIdx.y, b = blockIdx.z;

    const size_t qrow = (size_t)(b * Tt + t0 + 16 * wave + l15) * Dm + h * HD;
    const short8 qf0 = *(const short8*)&Qb[qrow + quad * 8];
    const short8 qf1 = *(const short8*)&Qb[qrow + 32 + quad * 8];

    f32x4 oacc[4] = {};
    float den[4] = {0.f, 0.f, 0.f, 0.f};
    const size_t kbase  = (size_t)(b * Tt) * Dm + h * HD;
    const size_t vtbase = (size_t)((b * NH + h) * HD) * Tt;

    for (int s0 = 0; s0 < Tt; s0 += 64) {
        for (int c = tid; c < 512; c += 256) {
            const int r = c >> 3, cc = (c & 7) * 8;
            *(short8*)&Ks[r][cc] = *(const short8*)&Kb[kbase + (size_t)(s0 + r) * Dm + cc];
            *(short8*)&Vs[r][cc] = *(const short8*)&Vtb[vtbase + (size_t)r * Tt + s0 + cc];
        }
        __syncthreads();

        // S = Q K^T
        f32x4 sf[4] = {};
        #pragma unroll
        for (int j = 0; j < 4; j++) {
            const short8 kf0 = *(const short8*)&Ks[16 * j + l15][quad * 8];
            const short8 kf1 = *(const short8*)&Ks[16 * j + l15][32 + quad * 8];
            sf[j] = __builtin_amdgcn_mfma_f32_16x16x32_bf16(qf0, kf0, sf[j], 0, 0, 0);
            sf[j] = __builtin_amdgcn_mfma_f32_16x16x32_bf16(qf1, kf1, sf[j], 0, 0, 0);
        }
        // angular transform (fast acos, A&S 4.4.45, |err|<=6.8e-5 rad).
        // After the +/-0.999 clip, s in [0.0142, 0.9858] so max(s,eps) is
        // provably a no-op -> omitted.
        #pragma unroll
        for (int j = 0; j < 4; j++)
            #pragma unroll
            for (int r = 0; r < 4; r++) {
                const float c = fminf(fmaxf(sf[j][r], -0.999f), 0.999f);
                const float ax = fabsf(c);
                float p = fmaf(-0.0187293f, ax, 0.0742610f);
                p = fmaf(p, ax, -0.2121144f);
                p = fmaf(p, ax, 1.5707288f);
                const float rp = sqrtf(1.f - ax) * p * INV_PI;  // acos(|c|)/pi
                const float s = (c >= 0.f) ? 1.f - rp : rp;
                const float p2 = s * s, p4 = p2 * p2, p8 = p4 * p4;
                const float w = p8 * p8;
                den[r] += w;
                Ws[16 * wave + quad * 4 + r][16 * j + l15] = f2bf(w);
            }
        __syncthreads();

        // O += W V
        const short8 wf0 = *(const short8*)&Ws[16 * wave + l15][quad * 8];
        const short8 wf1 = *(const short8*)&Ws[16 * wave + l15][32 + quad * 8];
        #pragma unroll
        for (int j = 0; j < 4; j++) {
            const short8 vf0 = *(const short8*)&Vs[16 * j + l15][quad * 8];
            const short8 vf1 = *(const short8*)&Vs[16 * j + l15][32 + quad * 8];
            oacc[j] = __builtin_amdgcn_mfma_f32_16x16x32_bf16(wf0, vf0, oacc[j], 0, 0, 0);
            oacc[j] = __builtin_amdgcn_mfma_f32_16x16x32_bf16(wf1, vf1, oacc[j], 0, 0, 0);
        }
        __syncthreads();
    }

    #pragma unroll
    for (int r = 0; r < 4; r++) {
        float d = den[r];
        d += __shfl_xor(d, 1); d += __shfl_xor(d, 2);
        d += __shfl_xor(d, 4); d += __shfl_xor(d, 8);
        den[r] = d;
    }
    const size_t obase = (size_t)(b * Tt + t0 + 16 * wave + quad * 4) * Dm + h * HD + l15;
    #pragma unroll
    for (int j = 0; j < 4; j++)
        #pragma unroll
        for (int r = 0; r < 4; r++)
            Ob[obase + (size_t)r * Dm + 16 * j] = f2bf(oacc[j][r] / (den[r] + EPSF));
}

// ---------------------------------------------------------------------------
extern "C" void kernel_launch(void* const* d_in, const int* in_sizes, int n_in,
                              void* d_out, int out_size, void* d_ws, size_t ws_size,
                              hipStream_t stream) {
    const float* x  = (const float*)d_in[0];
    const float* Wq = (const float*)d_in[1];
    const float* Wk = (const float*)d_in[2];
    const float* Wv = (const float*)d_in[3];
    const float* Wo = (const float*)d_in[4];
    const float* bo = (const float*)d_in[5];
    float* out = (float*)d_out;

    ushort* ws = (ushort*)d_ws;
    const size_t M1 = 1u << 20;
    ushort* xb  = ws;
    ushort* wqb = ws + 4 * M1;
    ushort* wkb = ws + 5 * M1;
    ushort* wvb = ws + 6 * M1;
    ushort* wob = ws + 7 * M1;
    ushort* qb  = ws + 8 * M1;
    ushort* kb  = ws + 12 * M1;
    ushort* vb  = ws + 16 * M1;
    ushort* vtb = ws + 20 * M1;
    ushort* aob = ws + 24 * M1;

    // 1) all converts in one launch
    cvt_all<<<8192, 256, 0, stream>>>(x, Wq, Wk, Wv, Wo, xb, wqb, wkb, wvb, wob);

    // 2) fused Q/K/V projection with in-epilogue L2 norm for Q,K
    qkv_gemm<<<dim3(MTOT / 128, 24), 256, 0, stream>>>(xb, wqb, wkb, wvb, qb, kb, vb);

    // 3) V^T
    vtranspose<<<dim3(Tt / 64, NH, Bb), 256, 0, stream>>>(vb, vtb);

    // 4) fused attention
    attn_kernel<<<dim3(Tt / 64, NH, Bb), 256, 0, stream>>>(qb, kb, vtb, aob);

    // 5) output projection + bias (fp32 out)
    out_gemm<<<dim3(MTOT / 128, Dm / 128), 256, 0, stream>>>(aob, wob, bo, out);
}

// Round 7
// 250.063 us; speedup vs baseline: 6.3284x; 1.1935x over previous
//
#include <hip/hip_runtime.h>
#include <math.h>

// Problem constants
constexpr int Dm   = 1024;
constexpr int NH   = 16;
constexpr int HD   = 64;
constexpr int Bb   = 2;
constexpr int Tt   = 2048;
constexpr int MTOT = Bb * Tt;   // 4096
#define EPSF 1e-6f

typedef __attribute__((ext_vector_type(8))) short short8;   // 8 x bf16
typedef __attribute__((ext_vector_type(4))) float f32x4;    // MFMA acc
typedef __attribute__((ext_vector_type(2))) float f32x2;    // packed fp32 pair

__device__ __forceinline__ ushort f2bf(float f) {
    union { float f; unsigned u; } v; v.f = f;
    unsigned r = (v.u + 0x7FFFu + ((v.u >> 16) & 1u)) >> 16;   // RNE
    return (ushort)r;
}

// async global->LDS, 16B/lane; LDS dest = wave-uniform base + lane*16
__device__ __forceinline__ void gload16(const void* g, void* l) {
    __builtin_amdgcn_global_load_lds(
        (const __attribute__((address_space(1))) unsigned int*)g,
        (__attribute__((address_space(3))) unsigned int*)l,
        16, 0, 0);
}

// ---------------------------------------------------------------------------
// fp32 -> bf16 for all five tensors in one launch.
// ---------------------------------------------------------------------------
__global__ __launch_bounds__(256)
void cvt_all(const float* __restrict__ x,  const float* __restrict__ wq,
             const float* __restrict__ wk, const float* __restrict__ wv,
             const float* __restrict__ wo,
             ushort* __restrict__ xb,  ushort* __restrict__ wqb,
             ushort* __restrict__ wkb, ushort* __restrict__ wvb,
             ushort* __restrict__ wob) {
    int i = blockIdx.x * 256 + threadIdx.x;   // float4 index
    const float* src; ushort* dst; int off;
    if (i < 1048576)      { src = x;  dst = xb;  off = i; }
    else if (i < 1310720) { src = wq; dst = wqb; off = i - 1048576; }
    else if (i < 1572864) { src = wk; dst = wkb; off = i - 1310720; }
    else if (i < 1835008) { src = wv; dst = wvb; off = i - 1572864; }
    else                  { src = wo; dst = wob; off = i - 1835008; }
    const float4 v = ((const float4*)src)[off];
    ushort4 o;
    o.x = f2bf(v.x); o.y = f2bf(v.y); o.z = f2bf(v.z); o.w = f2bf(v.w);
    ((ushort4*)dst)[off] = o;
}

// ---------------------------------------------------------------------------
// 128x128x(BK=64) bf16 MFMA GEMM core (m97-style, XOR-swizzled LDS).
// PROVEN in R3 — unchanged.
// ---------------------------------------------------------------------------
template<bool OUTF32>
__device__ __forceinline__
void gemm_core(const ushort* __restrict__ A, const ushort* __restrict__ W,
               const float* __restrict__ bias, void* __restrict__ out,
               int m0, int n0, int N, int K, bool do_norm) {
    __shared__ ushort As[128 * 64];
    __shared__ ushort Bs[128 * 64];
    const int tid  = threadIdx.x;
    const int wave = tid >> 6, lane = tid & 63;
    const int quad = lane >> 4, l15 = lane & 15;
    const int wr = wave >> 1, wc = wave & 1;
    const int lr = lane >> 3;
    const int sc = (lane & 7) ^ lr;

    f32x4 acc[4][4] = {};
    const ushort* Ab = A + (size_t)(m0 + lr) * K + sc * 8;
    const ushort* Wb = W + (size_t)(n0 + lr) * K + sc * 8;

    for (int k0 = 0; k0 < K; k0 += 64) {
        #pragma unroll
        for (int i = 0; i < 4; i++) {
            const int rows8 = (wave * 4 + i) * 8;
            gload16(Ab + (size_t)rows8 * K + k0, &As[rows8 * 64]);
            gload16(Wb + (size_t)rows8 * K + k0, &Bs[rows8 * 64]);
        }
        __syncthreads();
        #pragma unroll
        for (int kh = 0; kh < 2; kh++) {
            short8 af[4];
            #pragma unroll
            for (int mi = 0; mi < 4; mi++) {
                const int row = wr * 64 + mi * 16 + l15;
                af[mi] = *(const short8*)&As[row * 64 + (((kh * 4 + quad) ^ (row & 7)) * 8)];
            }
            #pragma unroll
            for (int nj = 0; nj < 4; nj++) {
                const int row = wc * 64 + nj * 16 + l15;
                const short8 bf = *(const short8*)&Bs[row * 64 + (((kh * 4 + quad) ^ (row & 7)) * 8)];
                #pragma unroll
                for (int mi = 0; mi < 4; mi++)
                    acc[mi][nj] = __builtin_amdgcn_mfma_f32_16x16x32_bf16(af[mi], bf, acc[mi][nj], 0, 0, 0);
            }
        }
        __syncthreads();
    }

    #pragma unroll
    for (int mi = 0; mi < 4; mi++) {
        float inv[4] = {1.f, 1.f, 1.f, 1.f};
        if (!OUTF32 && do_norm) {
            #pragma unroll
            for (int r = 0; r < 4; r++) {
                float ss = 0.f;
                #pragma unroll
                for (int nj = 0; nj < 4; nj++) ss += acc[mi][nj][r] * acc[mi][nj][r];
                ss += __shfl_xor(ss, 1); ss += __shfl_xor(ss, 2);
                ss += __shfl_xor(ss, 4); ss += __shfl_xor(ss, 8);
                inv[r] = 1.f / fmaxf(sqrtf(ss), EPSF);
            }
        }
        #pragma unroll
        for (int nj = 0; nj < 4; nj++)
            #pragma unroll
            for (int r = 0; r < 4; r++) {
                const int row = m0 + wr * 64 + mi * 16 + quad * 4 + r;
                const int col = n0 + wc * 64 + nj * 16 + l15;
                if (OUTF32)
                    ((float*)out)[(size_t)row * N + col] = acc[mi][nj][r] + bias[col];
                else
                    ((ushort*)out)[(size_t)row * N + col] = f2bf(acc[mi][nj][r] * inv[r]);
            }
    }
}

__global__ __launch_bounds__(256)
void qkv_gemm(const ushort* __restrict__ xb,
              const ushort* __restrict__ wq, const ushort* __restrict__ wk,
              const ushort* __restrict__ wv,
              ushort* __restrict__ qb, ushort* __restrict__ kb,
              ushort* __restrict__ vb) {
    const int ny = blockIdx.y, sel = ny >> 3;
    const ushort* W = (sel == 0) ? wq : (sel == 1) ? wk : wv;
    ushort* out     = (sel == 0) ? qb : (sel == 1) ? kb : vb;
    gemm_core<false>(xb, W, nullptr, out, blockIdx.x * 128, (ny & 7) * 128,
                     Dm, Dm, sel < 2);
}

__global__ __launch_bounds__(256)
void out_gemm(const ushort* __restrict__ aob, const ushort* __restrict__ wob,
              const float* __restrict__ bias, float* __restrict__ out) {
    gemm_core<true>(aob, wob, bias, out, blockIdx.x * 128, blockIdx.y * 128,
                    Dm, Dm, false);
}

// ---------------------------------------------------------------------------
// V [b,t,h*64+d] bf16 -> Vt [b,h,d,t] bf16 — R3 version (no permutation).
// ---------------------------------------------------------------------------
__global__ __launch_bounds__(256)
void vtranspose(const ushort* __restrict__ vb, ushort* __restrict__ vtb) {
    __shared__ ushort T[64][72];
    const int tid = threadIdx.x;
    const int s0 = blockIdx.x * 64, h = blockIdx.y, b = blockIdx.z;
    const size_t vtbase = (size_t)((b * NH + h) * HD) * Tt;
    for (int c = tid; c < 512; c += 256) {
        const int s = c >> 3, d0 = (c & 7) * 8;
        *(short8*)&T[s][d0] =
            *(const short8*)&vb[(size_t)(b * Tt + s0 + s) * Dm + h * HD + d0];
    }
    __syncthreads();
    for (int c = tid; c < 512; c += 256) {
        const int d = c >> 3, scol = (c & 7) * 8;
        short8 val;
        #pragma unroll
        for (int i = 0; i < 8; i++) val[i] = (short)T[scol + i][d];
        *(short8*)&vtb[vtbase + (size_t)d * Tt + s0 + scol] = val;
    }
}

// ---------------------------------------------------------------------------
// Fused angular attention — BISECT ROUND: this is the R3 (passing) kernel
// VERBATIM (padded [64][72] LDS, scalar short8 staging, full __syncthreads,
// f2bf RNE Ws writes) with exactly ONE delta: the transform block is the
// packed-f32x2 version. Pass -> gload16 attn staging was the bug.
// Fail -> packed transform is the bug.
// ---------------------------------------------------------------------------
__global__ __launch_bounds__(256)
void attn_kernel(const ushort* __restrict__ Qb, const ushort* __restrict__ Kb,
                 const ushort* __restrict__ Vtb, ushort* __restrict__ Ob) {
    __shared__ ushort Ks[64][72];
    __shared__ ushort Vs[64][72];   // V^T tile: rows d, cols s
    __shared__ ushort Ws[64][72];   // weight tile: rows q, cols s
    const int tid  = threadIdx.x;
    const int wave = tid >> 6, lane = tid & 63;
    const int quad = lane >> 4, l15 = lane & 15;
    const int t0 = blockIdx.x * 64, h = blockIdx.y, b = blockIdx.z;

    const size_t qrow = (size_t)(b * Tt + t0 + 16 * wave + l15) * Dm + h * HD;
    const short8 qf0 = *(const short8*)&Qb[qrow + quad * 8];
    const short8 qf1 = *(const short8*)&Qb[qrow + 32 + quad * 8];

    f32x4 oacc[4] = {};
    float den[4] = {0.f, 0.f, 0.f, 0.f};
    const size_t kbase  = (size_t)(b * Tt) * Dm + h * HD;
    const size_t vtbase = (size_t)((b * NH + h) * HD) * Tt;

    // acos(x)/pi ~ sqrt(1-x) * P(x), coeffs = A&S 4.4.45 / pi
    const f32x2 k3 = {-0.00596162f, -0.00596162f};
    const f32x2 k2 = { 0.02363680f,  0.02363680f};
    const f32x2 k1 = {-0.06751768f, -0.06751768f};
    const f32x2 k0 = { 0.49997415f,  0.49997415f};

    for (int s0 = 0; s0 < Tt; s0 += 64) {
        // R3 scalar staging (proven)
        for (int c = tid; c < 512; c += 256) {
            const int r = c >> 3, cc = (c & 7) * 8;
            *(short8*)&Ks[r][cc] = *(const short8*)&Kb[kbase + (size_t)(s0 + r) * Dm + cc];
            *(short8*)&Vs[r][cc] = *(const short8*)&Vtb[vtbase + (size_t)r * Tt + s0 + cc];
        }
        __syncthreads();

        // S = Q K^T (R3 verbatim)
        f32x4 sf[4] = {};
        #pragma unroll
        for (int j = 0; j < 4; j++) {
            const short8 kf0 = *(const short8*)&Ks[16 * j + l15][quad * 8];
            const short8 kf1 = *(const short8*)&Ks[16 * j + l15][32 + quad * 8];
            sf[j] = __builtin_amdgcn_mfma_f32_16x16x32_bf16(qf0, kf0, sf[j], 0, 0, 0);
            sf[j] = __builtin_amdgcn_mfma_f32_16x16x32_bf16(qf1, kf1, sf[j], 0, 0, 0);
        }

        // === packed transform (the single delta under test) ===
        #pragma unroll
        for (int r = 0; r < 4; r++) {
            f32x2 ca, cb;
            ca.x = __builtin_amdgcn_fmed3f(sf[0][r], -0.999f, 0.999f);
            ca.y = __builtin_amdgcn_fmed3f(sf[1][r], -0.999f, 0.999f);
            cb.x = __builtin_amdgcn_fmed3f(sf[2][r], -0.999f, 0.999f);
            cb.y = __builtin_amdgcn_fmed3f(sf[3][r], -0.999f, 0.999f);
            f32x2 axa = {fabsf(ca.x), fabsf(ca.y)};
            f32x2 axb = {fabsf(cb.x), fabsf(cb.y)};
            f32x2 pa = __builtin_elementwise_fma(axa, k3, k2);
            f32x2 pb = __builtin_elementwise_fma(axb, k3, k2);
            pa = __builtin_elementwise_fma(pa, axa, k1);
            pb = __builtin_elementwise_fma(pb, axb, k1);
            pa = __builtin_elementwise_fma(pa, axa, k0);
            pb = __builtin_elementwise_fma(pb, axb, k0);
            f32x2 ta = 1.0f - axa, tb = 1.0f - axb;
            ta.x = __builtin_amdgcn_sqrtf(ta.x); ta.y = __builtin_amdgcn_sqrtf(ta.y);
            tb.x = __builtin_amdgcn_sqrtf(tb.x); tb.y = __builtin_amdgcn_sqrtf(tb.y);
            const f32x2 rpa = ta * pa, rpb = tb * pb;      // acos(|c|)/pi <= 0.5
            const f32x2 da = 0.5f - rpa, db = 0.5f - rpb;  // >= 0
            f32x2 csa = {__builtin_copysignf(da.x, ca.x), __builtin_copysignf(da.y, ca.y)};
            f32x2 csb = {__builtin_copysignf(db.x, cb.x), __builtin_copysignf(db.y, cb.y)};
            f32x2 wa = csa + 0.5f, wb = csb + 0.5f;        // score s
            wa *= wa; wa *= wa; wa *= wa; wa *= wa;        // s^16
            wb *= wb; wb *= wb; wb *= wb; wb *= wb;
            den[r] += (wa.x + wa.y) + (wb.x + wb.y);
            const int wrow = 16 * wave + quad * 4 + r;
            Ws[wrow][l15]      = f2bf(wa.x);   // j = 0 -> col l15
            Ws[wrow][16 + l15] = f2bf(wa.y);   // j = 1
            Ws[wrow][32 + l15] = f2bf(wb.x);   // j = 2
            Ws[wrow][48 + l15] = f2bf(wb.y);   // j = 3
        }
        // === end delta ===
        __syncthreads();

        // O += W V (R3 verbatim)
        const short8 wf0 = *(const short8*)&Ws[16 * wave + l15][quad * 8];
        const short8 wf1 = *(const short8*)&Ws[16 * wave + l15][32 + quad * 8];
        #pragma unroll
        for (int j = 0; j < 4; j++) {
            const short8 vf0 = *(const short8*)&Vs[16 * j + l15][quad * 8];
            const short8 vf1 = *(const short8*)&Vs[16 * j + l15][32 + quad * 8];
            oacc[j] = __builtin_amdgcn_mfma_f32_16x16x32_bf16(wf0, vf0, oacc[j], 0, 0, 0);
            oacc[j] = __builtin_amdgcn_mfma_f32_16x16x32_bf16(wf1, vf1, oacc[j], 0, 0, 0);
        }
        __syncthreads();   // protect Ks/Vs/Ws before next tile
    }

    #pragma unroll
    for (int r = 0; r < 4; r++) {
        float d = den[r];
        d += __shfl_xor(d, 1); d += __shfl_xor(d, 2);
        d += __shfl_xor(d, 4); d += __shfl_xor(d, 8);
        den[r] = d;
    }
    const size_t obase = (size_t)(b * Tt + t0 + 16 * wave + quad * 4) * Dm + h * HD + l15;
    #pragma unroll
    for (int j = 0; j < 4; j++)
        #pragma unroll
        for (int r = 0; r < 4; r++)
            Ob[obase + (size_t)r * Dm + 16 * j] = f2bf(oacc[j][r] / (den[r] + EPSF));
}

// ---------------------------------------------------------------------------
extern "C" void kernel_launch(void* const* d_in, const int* in_sizes, int n_in,
                              void* d_out, int out_size, void* d_ws, size_t ws_size,
                              hipStream_t stream) {
    const float* x  = (const float*)d_in[0];
    const float* Wq = (const float*)d_in[1];
    const float* Wk = (const float*)d_in[2];
    const float* Wv = (const float*)d_in[3];
    const float* Wo = (const float*)d_in[4];
    const float* bo = (const float*)d_in[5];
    float* out = (float*)d_out;

    ushort* ws = (ushort*)d_ws;
    const size_t M1 = 1u << 20;
    ushort* xb  = ws;
    ushort* wqb = ws + 4 * M1;
    ushort* wkb = ws + 5 * M1;
    ushort* wvb = ws + 6 * M1;
    ushort* wob = ws + 7 * M1;
    ushort* qb  = ws + 8 * M1;
    ushort* kb  = ws + 12 * M1;
    ushort* vb  = ws + 16 * M1;
    ushort* vtb = ws + 20 * M1;
    ushort* aob = ws + 24 * M1;

    cvt_all<<<8192, 256, 0, stream>>>(x, Wq, Wk, Wv, Wo, xb, wqb, wkb, wvb, wob);
    qkv_gemm<<<dim3(MTOT / 128, 24), 256, 0, stream>>>(xb, wqb, wkb, wvb, qb, kb, vb);
    vtranspose<<<dim3(Tt / 64, NH, Bb), 256, 0, stream>>>(vb, vtb);
    attn_kernel<<<dim3(Tt / 64, NH, Bb), 256, 0, stream>>>(qb, kb, vtb, aob);
    out_gemm<<<dim3(MTOT / 128, Dm / 128), 256, 0, stream>>>(aob, wob, bo, out);
}

// Round 8
// 242.355 us; speedup vs baseline: 6.5297x; 1.0318x over previous
//
#include <hip/hip_runtime.h>
#include <math.h>

// Problem constants
constexpr int Dm   = 1024;
constexpr int NH   = 16;
constexpr int HD   = 64;
constexpr int Bb   = 2;
constexpr int Tt   = 2048;
constexpr int MTOT = Bb * Tt;   // 4096
#define EPSF 1e-6f

typedef __attribute__((ext_vector_type(8))) short short8;   // 8 x bf16
typedef __attribute__((ext_vector_type(4))) float f32x4;    // MFMA acc
typedef __attribute__((ext_vector_type(2))) float f32x2;    // packed fp32 pair

__device__ __forceinline__ ushort f2bf(float f) {
    union { float f; unsigned u; } v; v.f = f;
    unsigned r = (v.u + 0x7FFFu + ((v.u >> 16) & 1u)) >> 16;   // RNE
    return (ushort)r;
}

// async global->LDS, 16B/lane. PROVEN in gemm_core; CONVICTED in attn (R4-R6
// fails, R7 bisect) — do not use outside gemm_core.
__device__ __forceinline__ void gload16(const void* g, void* l) {
    __builtin_amdgcn_global_load_lds(
        (const __attribute__((address_space(1))) unsigned int*)g,
        (__attribute__((address_space(3))) unsigned int*)l,
        16, 0, 0);
}

// ---------------------------------------------------------------------------
// fp32 -> bf16 for all five tensors in one launch.
// ---------------------------------------------------------------------------
__global__ __launch_bounds__(256)
void cvt_all(const float* __restrict__ x,  const float* __restrict__ wq,
             const float* __restrict__ wk, const float* __restrict__ wv,
             const float* __restrict__ wo,
             ushort* __restrict__ xb,  ushort* __restrict__ wqb,
             ushort* __restrict__ wkb, ushort* __restrict__ wvb,
             ushort* __restrict__ wob) {
    int i = blockIdx.x * 256 + threadIdx.x;   // float4 index
    const float* src; ushort* dst; int off;
    if (i < 1048576)      { src = x;  dst = xb;  off = i; }
    else if (i < 1310720) { src = wq; dst = wqb; off = i - 1048576; }
    else if (i < 1572864) { src = wk; dst = wkb; off = i - 1310720; }
    else if (i < 1835008) { src = wv; dst = wvb; off = i - 1572864; }
    else                  { src = wo; dst = wob; off = i - 1835008; }
    const float4 v = ((const float4*)src)[off];
    ushort4 o;
    o.x = f2bf(v.x); o.y = f2bf(v.y); o.z = f2bf(v.z); o.w = f2bf(v.w);
    ((ushort4*)dst)[off] = o;
}

// ---------------------------------------------------------------------------
// 128x128x(BK=64) bf16 MFMA GEMM core (m97-style, XOR-swizzled LDS).
// PROVEN R3/R7 — unchanged.
// ---------------------------------------------------------------------------
template<bool OUTF32>
__device__ __forceinline__
void gemm_core(const ushort* __restrict__ A, const ushort* __restrict__ W,
               const float* __restrict__ bias, void* __restrict__ out,
               int m0, int n0, int N, int K, bool do_norm) {
    __shared__ ushort As[128 * 64];
    __shared__ ushort Bs[128 * 64];
    const int tid  = threadIdx.x;
    const int wave = tid >> 6, lane = tid & 63;
    const int quad = lane >> 4, l15 = lane & 15;
    const int wr = wave >> 1, wc = wave & 1;
    const int lr = lane >> 3;
    const int sc = (lane & 7) ^ lr;

    f32x4 acc[4][4] = {};
    const ushort* Ab = A + (size_t)(m0 + lr) * K + sc * 8;
    const ushort* Wb = W + (size_t)(n0 + lr) * K + sc * 8;

    for (int k0 = 0; k0 < K; k0 += 64) {
        #pragma unroll
        for (int i = 0; i < 4; i++) {
            const int rows8 = (wave * 4 + i) * 8;
            gload16(Ab + (size_t)rows8 * K + k0, &As[rows8 * 64]);
            gload16(Wb + (size_t)rows8 * K + k0, &Bs[rows8 * 64]);
        }
        __syncthreads();
        #pragma unroll
        for (int kh = 0; kh < 2; kh++) {
            short8 af[4];
            #pragma unroll
            for (int mi = 0; mi < 4; mi++) {
                const int row = wr * 64 + mi * 16 + l15;
                af[mi] = *(const short8*)&As[row * 64 + (((kh * 4 + quad) ^ (row & 7)) * 8)];
            }
            #pragma unroll
            for (int nj = 0; nj < 4; nj++) {
                const int row = wc * 64 + nj * 16 + l15;
                const short8 bf = *(const short8*)&Bs[row * 64 + (((kh * 4 + quad) ^ (row & 7)) * 8)];
                #pragma unroll
                for (int mi = 0; mi < 4; mi++)
                    acc[mi][nj] = __builtin_amdgcn_mfma_f32_16x16x32_bf16(af[mi], bf, acc[mi][nj], 0, 0, 0);
            }
        }
        __syncthreads();
    }

    #pragma unroll
    for (int mi = 0; mi < 4; mi++) {
        float inv[4] = {1.f, 1.f, 1.f, 1.f};
        if (!OUTF32 && do_norm) {
            #pragma unroll
            for (int r = 0; r < 4; r++) {
                float ss = 0.f;
                #pragma unroll
                for (int nj = 0; nj < 4; nj++) ss += acc[mi][nj][r] * acc[mi][nj][r];
                ss += __shfl_xor(ss, 1); ss += __shfl_xor(ss, 2);
                ss += __shfl_xor(ss, 4); ss += __shfl_xor(ss, 8);
                inv[r] = 1.f / fmaxf(sqrtf(ss), EPSF);
            }
        }
        #pragma unroll
        for (int nj = 0; nj < 4; nj++)
            #pragma unroll
            for (int r = 0; r < 4; r++) {
                const int row = m0 + wr * 64 + mi * 16 + quad * 4 + r;
                const int col = n0 + wc * 64 + nj * 16 + l15;
                if (OUTF32)
                    ((float*)out)[(size_t)row * N + col] = acc[mi][nj][r] + bias[col];
                else
                    ((ushort*)out)[(size_t)row * N + col] = f2bf(acc[mi][nj][r] * inv[r]);
            }
    }
}

__global__ __launch_bounds__(256)
void qkv_gemm(const ushort* __restrict__ xb,
              const ushort* __restrict__ wq, const ushort* __restrict__ wk,
              const ushort* __restrict__ wv,
              ushort* __restrict__ qb, ushort* __restrict__ kb,
              ushort* __restrict__ vb) {
    const int ny = blockIdx.y, sel = ny >> 3;
    const ushort* W = (sel == 0) ? wq : (sel == 1) ? wk : wv;
    ushort* out     = (sel == 0) ? qb : (sel == 1) ? kb : vb;
    gemm_core<false>(xb, W, nullptr, out, blockIdx.x * 128, (ny & 7) * 128,
                     Dm, Dm, sel < 2);
}

__global__ __launch_bounds__(256)
void out_gemm(const ushort* __restrict__ aob, const ushort* __restrict__ wob,
              const float* __restrict__ bias, float* __restrict__ out) {
    gemm_core<true>(aob, wob, bias, out, blockIdx.x * 128, blockIdx.y * 128,
                    Dm, Dm, false);
}

// ---------------------------------------------------------------------------
// V [b,t,h*64+d] bf16 -> Vt [b,h,d,t] bf16 — PROVEN R3/R7, unchanged.
// ---------------------------------------------------------------------------
__global__ __launch_bounds__(256)
void vtranspose(const ushort* __restrict__ vb, ushort* __restrict__ vtb) {
    __shared__ ushort T[64][72];
    const int tid = threadIdx.x;
    const int s0 = blockIdx.x * 64, h = blockIdx.y, b = blockIdx.z;
    const size_t vtbase = (size_t)((b * NH + h) * HD) * Tt;
    for (int c = tid; c < 512; c += 256) {
        const int s = c >> 3, d0 = (c & 7) * 8;
        *(short8*)&T[s][d0] =
            *(const short8*)&vb[(size_t)(b * Tt + s0 + s) * Dm + h * HD + d0];
    }
    __syncthreads();
    for (int c = tid; c < 512; c += 256) {
        const int d = c >> 3, scol = (c & 7) * 8;
        short8 val;
        #pragma unroll
        for (int i = 0; i < 8; i++) val[i] = (short)T[scol + i][d];
        *(short8*)&vtb[vtbase + (size_t)d * Tt + s0 + scol] = val;
    }
}

// ---------------------------------------------------------------------------
// Fused angular attention, R8: 128-query blocks (wave owns 32 q-rows),
// double-buffered K/V LDS with register prefetch (scalar short8 loads +
// per-lane ds_write_b128 — NO gload16 here), XOR-swizzled unpadded tiles,
// packed transform (R7-proven). 2 barriers per K-tile.
// ---------------------------------------------------------------------------
__global__ __launch_bounds__(256)
void attn_kernel(const ushort* __restrict__ Qb, const ushort* __restrict__ Kb,
                 const ushort* __restrict__ Vtb, ushort* __restrict__ Ob) {
    __shared__ ushort Ks[2][64 * 64];
    __shared__ ushort Vs[2][64 * 64];
    __shared__ ushort Ws[128 * 64];
    const int tid  = threadIdx.x;
    const int wave = tid >> 6, lane = tid & 63;
    const int quad = lane >> 4, l15 = lane & 15;
    const int t0 = blockIdx.x * 128, h = blockIdx.y, b = blockIdx.z;

    // Q A-fragments: wave owns q-rows 32*wave .. 32*wave+31 (2 m-subtiles)
    short8 qf[2][2];
    #pragma unroll
    for (int mi = 0; mi < 2; mi++) {
        const size_t qrow =
            (size_t)(b * Tt + t0 + 32 * wave + 16 * mi + l15) * Dm + h * HD;
        qf[mi][0] = *(const short8*)&Qb[qrow + quad * 8];
        qf[mi][1] = *(const short8*)&Qb[qrow + 32 + quad * 8];
    }

    const size_t kbase  = (size_t)(b * Tt) * Dm + h * HD;
    const size_t vtbase = (size_t)((b * NH + h) * HD) * Tt;
    // staging: thread covers (row r0, chunk ch0) and (row r0+32, chunk ch0)
    const int r0 = tid >> 3, ch0 = tid & 7;
    const ushort* kg = Kb  + kbase  + (size_t)r0 * Dm + ch0 * 8;
    const ushort* vg = Vtb + vtbase + (size_t)r0 * Tt + ch0 * 8;
    const int lsw0 = r0 * 64 + ((ch0 ^ (r0 & 7)) * 8);          // LDS[r][c^(r&7)]
    const int lsw1 = (r0 + 32) * 64 + ((ch0 ^ (r0 & 7)) * 8);   // (r0+32)&7 == r0&7

    f32x4 oacc[2][4] = {};
    f32x2 denp[2][4] = {};

    // acos(x)/pi ~ sqrt(1-x) * P(x), coeffs = A&S 4.4.45 / pi
    const f32x2 k3 = {-0.00596162f, -0.00596162f};
    const f32x2 k2 = { 0.02363680f,  0.02363680f};
    const f32x2 k1 = {-0.06751768f, -0.06751768f};
    const f32x2 k0 = { 0.49997415f,  0.49997415f};

    // prologue: stage tile 0 into buffer 0
    short8 pk0 = *(const short8*)kg;
    short8 pk1 = *(const short8*)(kg + (size_t)32 * Dm);
    short8 pv0 = *(const short8*)vg;
    short8 pv1 = *(const short8*)(vg + (size_t)32 * Tt);
    *(short8*)&Ks[0][lsw0] = pk0;  *(short8*)&Ks[0][lsw1] = pk1;
    *(short8*)&Vs[0][lsw0] = pv0;  *(short8*)&Vs[0][lsw1] = pv1;
    __syncthreads();

    for (int i = 0; i < 32; i++) {
        const int p = i & 1;
        if (i < 31) {   // prefetch next tile into registers (latency overlaps body)
            const size_t sn = (size_t)(i + 1) * 64;
            pk0 = *(const short8*)(kg + sn * Dm);
            pk1 = *(const short8*)(kg + (sn + 32) * Dm);
            pv0 = *(const short8*)(vg + sn);
            pv1 = *(const short8*)(vg + sn + (size_t)32 * Tt);
        }

        // S = Q K^T : K-frags shared across both m-subtiles
        f32x4 sf[2][4] = {};
        #pragma unroll
        for (int j = 0; j < 4; j++) {
            const int row = 16 * j + l15;
            const short8 kf0 = *(const short8*)&Ks[p][row * 64 + ((quad ^ (row & 7)) * 8)];
            const short8 kf1 = *(const short8*)&Ks[p][row * 64 + (((4 + quad) ^ (row & 7)) * 8)];
            #pragma unroll
            for (int mi = 0; mi < 2; mi++) {
                sf[mi][j] = __builtin_amdgcn_mfma_f32_16x16x32_bf16(qf[mi][0], kf0, sf[mi][j], 0, 0, 0);
                sf[mi][j] = __builtin_amdgcn_mfma_f32_16x16x32_bf16(qf[mi][1], kf1, sf[mi][j], 0, 0, 0);
            }
        }

        // packed angular transform (R7-proven), Ws writes XOR-swizzled
        #pragma unroll
        for (int mi = 0; mi < 2; mi++)
            #pragma unroll
            for (int r = 0; r < 4; r++) {
                f32x2 ca, cb;
                ca.x = __builtin_amdgcn_fmed3f(sf[mi][0][r], -0.999f, 0.999f);
                ca.y = __builtin_amdgcn_fmed3f(sf[mi][1][r], -0.999f, 0.999f);
                cb.x = __builtin_amdgcn_fmed3f(sf[mi][2][r], -0.999f, 0.999f);
                cb.y = __builtin_amdgcn_fmed3f(sf[mi][3][r], -0.999f, 0.999f);
                f32x2 axa = {fabsf(ca.x), fabsf(ca.y)};
                f32x2 axb = {fabsf(cb.x), fabsf(cb.y)};
                f32x2 pa = __builtin_elementwise_fma(axa, k3, k2);
                f32x2 pb = __builtin_elementwise_fma(axb, k3, k2);
                pa = __builtin_elementwise_fma(pa, axa, k1);
                pb = __builtin_elementwise_fma(pb, axb, k1);
                pa = __builtin_elementwise_fma(pa, axa, k0);
                pb = __builtin_elementwise_fma(pb, axb, k0);
                f32x2 ta = 1.0f - axa, tb = 1.0f - axb;
                ta.x = __builtin_amdgcn_sqrtf(ta.x); ta.y = __builtin_amdgcn_sqrtf(ta.y);
                tb.x = __builtin_amdgcn_sqrtf(tb.x); tb.y = __builtin_amdgcn_sqrtf(tb.y);
                const f32x2 rpa = ta * pa, rpb = tb * pb;      // acos(|c|)/pi <= 0.5
                const f32x2 da = 0.5f - rpa, db = 0.5f - rpb;  // >= 0
                f32x2 csa = {__builtin_copysignf(da.x, ca.x), __builtin_copysignf(da.y, ca.y)};
                f32x2 csb = {__builtin_copysignf(db.x, cb.x), __builtin_copysignf(db.y, cb.y)};
                f32x2 wa = csa + 0.5f, wb = csb + 0.5f;        // score s
                wa *= wa; wa *= wa; wa *= wa; wa *= wa;        // s^16
                wb *= wb; wb *= wb; wb *= wb; wb *= wb;
                denp[mi][r] += wa; denp[mi][r] += wb;
                const int wrow = 32 * wave + 16 * mi + quad * 4 + r;
                const int wb7 = wrow & 7;
                const int base = wrow * 64 + (l15 & 7);
                const int hc = l15 >> 3;                        // col chunk = 2j + hc
                Ws[base + (((hc)     ^ wb7) * 8)] = f2bf(wa.x); // j=0: col l15
                Ws[base + (((hc + 2) ^ wb7) * 8)] = f2bf(wa.y); // j=1: col 16+l15
                Ws[base + (((hc + 4) ^ wb7) * 8)] = f2bf(wb.x); // j=2: col 32+l15
                Ws[base + (((hc + 6) ^ wb7) * 8)] = f2bf(wb.y); // j=3: col 48+l15
            }
        __syncthreads();   // A: Ws ready (also drains prefetch vmcnt)

        // O += W V : V-frags shared across both m-subtiles
        short8 wf[2][2];
        #pragma unroll
        for (int mi = 0; mi < 2; mi++) {
            const int wrow = 32 * wave + 16 * mi + l15;
            wf[mi][0] = *(const short8*)&Ws[wrow * 64 + ((quad ^ (wrow & 7)) * 8)];
            wf[mi][1] = *(const short8*)&Ws[wrow * 64 + (((4 + quad) ^ (wrow & 7)) * 8)];
        }
        #pragma unroll
        for (int j = 0; j < 4; j++) {
            const int vrow = 16 * j + l15;
            const short8 vf0 = *(const short8*)&Vs[p][vrow * 64 + ((quad ^ (vrow & 7)) * 8)];
            const short8 vf1 = *(const short8*)&Vs[p][vrow * 64 + (((4 + quad) ^ (vrow & 7)) * 8)];
            #pragma unroll
            for (int mi = 0; mi < 2; mi++) {
                oacc[mi][j] = __builtin_amdgcn_mfma_f32_16x16x32_bf16(wf[mi][0], vf0, oacc[mi][j], 0, 0, 0);
                oacc[mi][j] = __builtin_amdgcn_mfma_f32_16x16x32_bf16(wf[mi][1], vf1, oacc[mi][j], 0, 0, 0);
            }
        }
        // commit prefetched tile into the other buffer (read in iter i+1)
        if (i < 31) {
            *(short8*)&Ks[1 - p][lsw0] = pk0;  *(short8*)&Ks[1 - p][lsw1] = pk1;
            *(short8*)&Vs[1 - p][lsw0] = pv0;  *(short8*)&Vs[1 - p][lsw1] = pv1;
        }
        __syncthreads();   // B: staging visible; Ws/Vs reads done everywhere
    }

    // epilogue
    #pragma unroll
    for (int mi = 0; mi < 2; mi++) {
        float den[4];
        #pragma unroll
        for (int r = 0; r < 4; r++) {
            float d = denp[mi][r].x + denp[mi][r].y;
            d += __shfl_xor(d, 1); d += __shfl_xor(d, 2);
            d += __shfl_xor(d, 4); d += __shfl_xor(d, 8);
            den[r] = d;
        }
        const size_t obase =
            (size_t)(b * Tt + t0 + 32 * wave + 16 * mi + quad * 4) * Dm + h * HD + l15;
        #pragma unroll
        for (int j = 0; j < 4; j++)
            #pragma unroll
            for (int r = 0; r < 4; r++)
                Ob[obase + (size_t)r * Dm + 16 * j] =
                    f2bf(oacc[mi][j][r] / (den[r] + EPSF));
    }
}

// ---------------------------------------------------------------------------
extern "C" void kernel_launch(void* const* d_in, const int* in_sizes, int n_in,
                              void* d_out, int out_size, void* d_ws, size_t ws_size,
                              hipStream_t stream) {
    const float* x  = (const float*)d_in[0];
    const float* Wq = (const float*)d_in[1];
    const float* Wk = (const float*)d_in[2];
    const float* Wv = (const float*)d_in[3];
    const float* Wo = (const float*)d_in[4];
    const float* bo = (const float*)d_in[5];
    float* out = (float*)d_out;

    ushort* ws = (ushort*)d_ws;
    const size_t M1 = 1u << 20;
    ushort* xb  = ws;
    ushort* wqb = ws + 4 * M1;
    ushort* wkb = ws + 5 * M1;
    ushort* wvb = ws + 6 * M1;
    ushort* wob = ws + 7 * M1;
    ushort* qb  = ws + 8 * M1;
    ushort* kb  = ws + 12 * M1;
    ushort* vb  = ws + 16 * M1;
    ushort* vtb = ws + 20 * M1;
    ushort* aob = ws + 24 * M1;

    cvt_all<<<8192, 256, 0, stream>>>(x, Wq, Wk, Wv, Wo, xb, wqb, wkb, wvb, wob);
    qkv_gemm<<<dim3(MTOT / 128, 24), 256, 0, stream>>>(xb, wqb, wkb, wvb, qb, kb, vb);
    vtranspose<<<dim3(Tt / 64, NH, Bb), 256, 0, stream>>>(vb, vtb);
    attn_kernel<<<dim3(Tt / 128, NH, Bb), 256, 0, stream>>>(qb, kb, vtb, aob);
    out_gemm<<<dim3(MTOT / 128, Dm / 128), 256, 0, stream>>>(aob, wob, bo, out);
}

// Round 9
// 236.400 us; speedup vs baseline: 6.6942x; 1.0252x over previous
//
#include <hip/hip_runtime.h>
#include <math.h>

// Problem constants
constexpr int Dm   = 1024;
constexpr int NH   = 16;
constexpr int HD   = 64;
constexpr int Bb   = 2;
constexpr int Tt   = 2048;
constexpr int MTOT = Bb * Tt;   // 4096
#define EPSF 1e-6f

typedef __attribute__((ext_vector_type(8))) short short8;   // 8 x bf16
typedef __attribute__((ext_vector_type(4))) float f32x4;    // MFMA acc
typedef __attribute__((ext_vector_type(2))) float f32x2;    // packed fp32 pair

__device__ __forceinline__ ushort f2bf(float f) {
    union { float f; unsigned u; } v; v.f = f;
    unsigned r = (v.u + 0x7FFFu + ((v.u >> 16) & 1u)) >> 16;   // RNE
    return (ushort)r;
}

// async global->LDS, 16B/lane. PROVEN in gemm_core; CONVICTED in attn (R4-R6
// fails, R7 bisect) — do not use outside gemm_core.
__device__ __forceinline__ void gload16(const void* g, void* l) {
    __builtin_amdgcn_global_load_lds(
        (const __attribute__((address_space(1))) unsigned int*)g,
        (__attribute__((address_space(3))) unsigned int*)l,
        16, 0, 0);
}

// ---------------------------------------------------------------------------
// fp32 -> bf16 for all five tensors in one launch.
// ---------------------------------------------------------------------------
__global__ __launch_bounds__(256)
void cvt_all(const float* __restrict__ x,  const float* __restrict__ wq,
             const float* __restrict__ wk, const float* __restrict__ wv,
             const float* __restrict__ wo,
             ushort* __restrict__ xb,  ushort* __restrict__ wqb,
             ushort* __restrict__ wkb, ushort* __restrict__ wvb,
             ushort* __restrict__ wob) {
    int i = blockIdx.x * 256 + threadIdx.x;   // float4 index
    const float* src; ushort* dst; int off;
    if (i < 1048576)      { src = x;  dst = xb;  off = i; }
    else if (i < 1310720) { src = wq; dst = wqb; off = i - 1048576; }
    else if (i < 1572864) { src = wk; dst = wkb; off = i - 1310720; }
    else if (i < 1835008) { src = wv; dst = wvb; off = i - 1572864; }
    else                  { src = wo; dst = wob; off = i - 1835008; }
    const float4 v = ((const float4*)src)[off];
    ushort4 o;
    o.x = f2bf(v.x); o.y = f2bf(v.y); o.z = f2bf(v.z); o.w = f2bf(v.w);
    ((ushort4*)dst)[off] = o;
}

// ---------------------------------------------------------------------------
// 128x128x(BK=64) bf16 MFMA GEMM core (m97-style, XOR-swizzled LDS).
// PROVEN R3/R7/R8. mode: 0 = plain bf16 out (or fp32+bias if OUTF32),
// 1 = bf16 out with per-64col L2 norm (Q/K), 2 = V: write C^T per head into
// Vt[b,h,d,t] via packed uint2 stores (4 consecutive t per lane-fragment).
// ---------------------------------------------------------------------------
template<bool OUTF32>
__device__ __forceinline__
void gemm_core(const ushort* __restrict__ A, const ushort* __restrict__ W,
               const float* __restrict__ bias, void* __restrict__ out,
               int m0, int n0, int N, int K, int mode) {
    __shared__ ushort As[128 * 64];
    __shared__ ushort Bs[128 * 64];
    const int tid  = threadIdx.x;
    const int wave = tid >> 6, lane = tid & 63;
    const int quad = lane >> 4, l15 = lane & 15;
    const int wr = wave >> 1, wc = wave & 1;
    const int lr = lane >> 3;
    const int sc = (lane & 7) ^ lr;

    f32x4 acc[4][4] = {};
    const ushort* Ab = A + (size_t)(m0 + lr) * K + sc * 8;
    const ushort* Wb = W + (size_t)(n0 + lr) * K + sc * 8;

    for (int k0 = 0; k0 < K; k0 += 64) {
        #pragma unroll
        for (int i = 0; i < 4; i++) {
            const int rows8 = (wave * 4 + i) * 8;
            gload16(Ab + (size_t)rows8 * K + k0, &As[rows8 * 64]);
            gload16(Wb + (size_t)rows8 * K + k0, &Bs[rows8 * 64]);
        }
        __syncthreads();
        #pragma unroll
        for (int kh = 0; kh < 2; kh++) {
            short8 af[4];
            #pragma unroll
            for (int mi = 0; mi < 4; mi++) {
                const int row = wr * 64 + mi * 16 + l15;
                af[mi] = *(const short8*)&As[row * 64 + (((kh * 4 + quad) ^ (row & 7)) * 8)];
            }
            #pragma unroll
            for (int nj = 0; nj < 4; nj++) {
                const int row = wc * 64 + nj * 16 + l15;
                const short8 bf = *(const short8*)&Bs[row * 64 + (((kh * 4 + quad) ^ (row & 7)) * 8)];
                #pragma unroll
                for (int mi = 0; mi < 4; mi++)
                    acc[mi][nj] = __builtin_amdgcn_mfma_f32_16x16x32_bf16(af[mi], bf, acc[mi][nj], 0, 0, 0);
            }
        }
        __syncthreads();
    }

    if (!OUTF32 && mode == 2) {
        // V path: Vt[((b*NH+h)*HD+d)*Tt + t]; lane frag = 4 consecutive t
        #pragma unroll
        for (int mi = 0; mi < 4; mi++) {
            const int t  = m0 + wr * 64 + mi * 16 + quad * 4;
            const int bb = t >> 11, tl = t & 2047;
            #pragma unroll
            for (int nj = 0; nj < 4; nj++) {
                const int n = n0 + wc * 64 + nj * 16 + l15;
                const int hh = n >> 6, dd = n & 63;
                uint2 pk;
                pk.x = (unsigned)f2bf(acc[mi][nj][0]) | ((unsigned)f2bf(acc[mi][nj][1]) << 16);
                pk.y = (unsigned)f2bf(acc[mi][nj][2]) | ((unsigned)f2bf(acc[mi][nj][3]) << 16);
                *(uint2*)&((ushort*)out)[(size_t)((bb * NH + hh) * HD + dd) * Tt + tl] = pk;
            }
        }
        return;
    }

    #pragma unroll
    for (int mi = 0; mi < 4; mi++) {
        float inv[4] = {1.f, 1.f, 1.f, 1.f};
        if (!OUTF32 && mode == 1) {
            #pragma unroll
            for (int r = 0; r < 4; r++) {
                float ss = 0.f;
                #pragma unroll
                for (int nj = 0; nj < 4; nj++) ss += acc[mi][nj][r] * acc[mi][nj][r];
                ss += __shfl_xor(ss, 1); ss += __shfl_xor(ss, 2);
                ss += __shfl_xor(ss, 4); ss += __shfl_xor(ss, 8);
                inv[r] = 1.f / fmaxf(sqrtf(ss), EPSF);
            }
        }
        #pragma unroll
        for (int nj = 0; nj < 4; nj++)
            #pragma unroll
            for (int r = 0; r < 4; r++) {
                const int row = m0 + wr * 64 + mi * 16 + quad * 4 + r;
                const int col = n0 + wc * 64 + nj * 16 + l15;
                if (OUTF32)
                    ((float*)out)[(size_t)row * N + col] = acc[mi][nj][r] + bias[col];
                else
                    ((ushort*)out)[(size_t)row * N + col] = f2bf(acc[mi][nj][r] * inv[r]);
            }
    }
}

// Q/K: normed bf16 out; V: direct-transposed into vtb (drops vtranspose).
__global__ __launch_bounds__(256)
void qkv_gemm(const ushort* __restrict__ xb,
              const ushort* __restrict__ wq, const ushort* __restrict__ wk,
              const ushort* __restrict__ wv,
              ushort* __restrict__ qb, ushort* __restrict__ kb,
              ushort* __restrict__ vtb) {
    const int ny = blockIdx.y, sel = ny >> 3;
    const ushort* W = (sel == 0) ? wq : (sel == 1) ? wk : wv;
    ushort* out     = (sel == 0) ? qb : (sel == 1) ? kb : vtb;
    gemm_core<false>(xb, W, nullptr, out, blockIdx.x * 128, (ny & 7) * 128,
                     Dm, Dm, (sel < 2) ? 1 : 2);
}

__global__ __launch_bounds__(256)
void out_gemm(const ushort* __restrict__ aob, const ushort* __restrict__ wob,
              const float* __restrict__ bias, float* __restrict__ out) {
    gemm_core<true>(aob, wob, bias, out, blockIdx.x * 128, blockIdx.y * 128,
                    Dm, Dm, 0);
}

// ---------------------------------------------------------------------------
// Fused angular attention, R9: 64-query tiles (grid 1024 -> 4 blocks/CU,
// LDS 40KB), wave owns 16 q-rows. R8 machinery kept: register-prefetch
// double-buffered K/V, XOR-swizzled unpadded tiles, packed transform.
// ---------------------------------------------------------------------------
__global__ __launch_bounds__(256)
void attn_kernel(const ushort* __restrict__ Qb, const ushort* __restrict__ Kb,
                 const ushort* __restrict__ Vtb, ushort* __restrict__ Ob) {
    __shared__ ushort Ks[2][64 * 64];
    __shared__ ushort Vs[2][64 * 64];
    __shared__ ushort Ws[64 * 64];
    const int tid  = threadIdx.x;
    const int wave = tid >> 6, lane = tid & 63;
    const int quad = lane >> 4, l15 = lane & 15;
    const int t0 = blockIdx.x * 64, h = blockIdx.y, b = blockIdx.z;

    // Q A-fragments: wave owns q-rows 16*wave .. 16*wave+15
    const size_t qrow = (size_t)(b * Tt + t0 + 16 * wave + l15) * Dm + h * HD;
    const short8 qf0 = *(const short8*)&Qb[qrow + quad * 8];
    const short8 qf1 = *(const short8*)&Qb[qrow + 32 + quad * 8];

    const size_t kbase  = (size_t)(b * Tt) * Dm + h * HD;
    const size_t vtbase = (size_t)((b * NH + h) * HD) * Tt;
    // staging: thread covers (row r0, chunk ch0) and (row r0+32, chunk ch0)
    const int r0 = tid >> 3, ch0 = tid & 7;
    const ushort* kg = Kb  + kbase  + (size_t)r0 * Dm + ch0 * 8;
    const ushort* vg = Vtb + vtbase + (size_t)r0 * Tt + ch0 * 8;
    const int lsw0 = r0 * 64 + ((ch0 ^ (r0 & 7)) * 8);          // LDS[r][c^(r&7)]
    const int lsw1 = (r0 + 32) * 64 + ((ch0 ^ (r0 & 7)) * 8);   // (r0+32)&7 == r0&7

    f32x4 oacc[4] = {};
    f32x2 denp[4] = {};

    // acos(x)/pi ~ sqrt(1-x) * P(x), coeffs = A&S 4.4.45 / pi
    const f32x2 k3 = {-0.00596162f, -0.00596162f};
    const f32x2 k2 = { 0.02363680f,  0.02363680f};
    const f32x2 k1 = {-0.06751768f, -0.06751768f};
    const f32x2 k0 = { 0.49997415f,  0.49997415f};

    // prologue: stage tile 0 into buffer 0
    short8 pk0 = *(const short8*)kg;
    short8 pk1 = *(const short8*)(kg + (size_t)32 * Dm);
    short8 pv0 = *(const short8*)vg;
    short8 pv1 = *(const short8*)(vg + (size_t)32 * Tt);
    *(short8*)&Ks[0][lsw0] = pk0;  *(short8*)&Ks[0][lsw1] = pk1;
    *(short8*)&Vs[0][lsw0] = pv0;  *(short8*)&Vs[0][lsw1] = pv1;
    __syncthreads();

    for (int i = 0; i < 32; i++) {
        const int p = i & 1;
        if (i < 31) {   // prefetch next tile into registers
            const size_t sn = (size_t)(i + 1) * 64;
            pk0 = *(const short8*)(kg + sn * Dm);
            pk1 = *(const short8*)(kg + (sn + 32) * Dm);
            pv0 = *(const short8*)(vg + sn);
            pv1 = *(const short8*)(vg + sn + (size_t)32 * Tt);
        }

        // S = Q K^T
        f32x4 sf[4] = {};
        #pragma unroll
        for (int j = 0; j < 4; j++) {
            const int row = 16 * j + l15;
            const short8 kf0 = *(const short8*)&Ks[p][row * 64 + ((quad ^ (row & 7)) * 8)];
            const short8 kf1 = *(const short8*)&Ks[p][row * 64 + (((4 + quad) ^ (row & 7)) * 8)];
            sf[j] = __builtin_amdgcn_mfma_f32_16x16x32_bf16(qf0, kf0, sf[j], 0, 0, 0);
            sf[j] = __builtin_amdgcn_mfma_f32_16x16x32_bf16(qf1, kf1, sf[j], 0, 0, 0);
        }

        // packed angular transform (R7-proven), Ws writes XOR-swizzled
        #pragma unroll
        for (int r = 0; r < 4; r++) {
            f32x2 ca, cb;
            ca.x = __builtin_amdgcn_fmed3f(sf[0][r], -0.999f, 0.999f);
            ca.y = __builtin_amdgcn_fmed3f(sf[1][r], -0.999f, 0.999f);
            cb.x = __builtin_amdgcn_fmed3f(sf[2][r], -0.999f, 0.999f);
            cb.y = __builtin_amdgcn_fmed3f(sf[3][r], -0.999f, 0.999f);
            f32x2 axa = {fabsf(ca.x), fabsf(ca.y)};
            f32x2 axb = {fabsf(cb.x), fabsf(cb.y)};
            f32x2 pa = __builtin_elementwise_fma(axa, k3, k2);
            f32x2 pb = __builtin_elementwise_fma(axb, k3, k2);
            pa = __builtin_elementwise_fma(pa, axa, k1);
            pb = __builtin_elementwise_fma(pb, axb, k1);
            pa = __builtin_elementwise_fma(pa, axa, k0);
            pb = __builtin_elementwise_fma(pb, axb, k0);
            f32x2 ta = 1.0f - axa, tb = 1.0f - axb;
            ta.x = __builtin_amdgcn_sqrtf(ta.x); ta.y = __builtin_amdgcn_sqrtf(ta.y);
            tb.x = __builtin_amdgcn_sqrtf(tb.x); tb.y = __builtin_amdgcn_sqrtf(tb.y);
            const f32x2 rpa = ta * pa, rpb = tb * pb;      // acos(|c|)/pi <= 0.5
            const f32x2 da = 0.5f - rpa, db = 0.5f - rpb;  // >= 0
            f32x2 csa = {__builtin_copysignf(da.x, ca.x), __builtin_copysignf(da.y, ca.y)};
            f32x2 csb = {__builtin_copysignf(db.x, cb.x), __builtin_copysignf(db.y, cb.y)};
            f32x2 wa = csa + 0.5f, wb = csb + 0.5f;        // score s
            wa *= wa; wa *= wa; wa *= wa; wa *= wa;        // s^16
            wb *= wb; wb *= wb; wb *= wb; wb *= wb;
            denp[r] += wa; denp[r] += wb;
            const int wrow = 16 * wave + quad * 4 + r;
            const int wb7 = wrow & 7;
            const int base = wrow * 64 + (l15 & 7);
            const int hc = l15 >> 3;                        // col chunk = 2j + hc
            Ws[base + (((hc)     ^ wb7) * 8)] = f2bf(wa.x); // j=0: col l15
            Ws[base + (((hc + 2) ^ wb7) * 8)] = f2bf(wa.y); // j=1: col 16+l15
            Ws[base + (((hc + 4) ^ wb7) * 8)] = f2bf(wb.x); // j=2: col 32+l15
            Ws[base + (((hc + 6) ^ wb7) * 8)] = f2bf(wb.y); // j=3: col 48+l15
        }
        __syncthreads();   // A: Ws ready

        // O += W V
        const int wrow = 16 * wave + l15;
        const short8 wf0 = *(const short8*)&Ws[wrow * 64 + ((quad ^ (wrow & 7)) * 8)];
        const short8 wf1 = *(const short8*)&Ws[wrow * 64 + (((4 + quad) ^ (wrow & 7)) * 8)];
        #pragma unroll
        for (int j = 0; j < 4; j++) {
            const int vrow = 16 * j + l15;
            const short8 vf0 = *(const short8*)&Vs[p][vrow * 64 + ((quad ^ (vrow & 7)) * 8)];
            const short8 vf1 = *(const short8*)&Vs[p][vrow * 64 + (((4 + quad) ^ (vrow & 7)) * 8)];
            oacc[j] = __builtin_amdgcn_mfma_f32_16x16x32_bf16(wf0, vf0, oacc[j], 0, 0, 0);
            oacc[j] = __builtin_amdgcn_mfma_f32_16x16x32_bf16(wf1, vf1, oacc[j], 0, 0, 0);
        }
        // commit prefetched tile into the other buffer (read in iter i+1)
        if (i < 31) {
            *(short8*)&Ks[1 - p][lsw0] = pk0;  *(short8*)&Ks[1 - p][lsw1] = pk1;
            *(short8*)&Vs[1 - p][lsw0] = pv0;  *(short8*)&Vs[1 - p][lsw1] = pv1;
        }
        __syncthreads();   // B: staging visible; Ws/Vs reads done everywhere
    }

    // epilogue
    float den[4];
    #pragma unroll
    for (int r = 0; r < 4; r++) {
        float d = denp[r].x + denp[r].y;
        d += __shfl_xor(d, 1); d += __shfl_xor(d, 2);
        d += __shfl_xor(d, 4); d += __shfl_xor(d, 8);
        den[r] = d;
    }
    const size_t obase =
        (size_t)(b * Tt + t0 + 16 * wave + quad * 4) * Dm + h * HD + l15;
    #pragma unroll
    for (int j = 0; j < 4; j++)
        #pragma unroll
        for (int r = 0; r < 4; r++)
            Ob[obase + (size_t)r * Dm + 16 * j] = f2bf(oacc[j][r] / (den[r] + EPSF));
}

// ---------------------------------------------------------------------------
extern "C" void kernel_launch(void* const* d_in, const int* in_sizes, int n_in,
                              void* d_out, int out_size, void* d_ws, size_t ws_size,
                              hipStream_t stream) {
    const float* x  = (const float*)d_in[0];
    const float* Wq = (const float*)d_in[1];
    const float* Wk = (const float*)d_in[2];
    const float* Wv = (const float*)d_in[3];
    const float* Wo = (const float*)d_in[4];
    const float* bo = (const float*)d_in[5];
    float* out = (float*)d_out;

    ushort* ws = (ushort*)d_ws;
    const size_t M1 = 1u << 20;
    ushort* xb  = ws;
    ushort* wqb = ws + 4 * M1;
    ushort* wkb = ws + 5 * M1;
    ushort* wvb = ws + 6 * M1;
    ushort* wob = ws + 7 * M1;
    ushort* qb  = ws + 8 * M1;
    ushort* kb  = ws + 12 * M1;
    ushort* vtb = ws + 16 * M1;
    ushort* aob = ws + 20 * M1;

    cvt_all<<<8192, 256, 0, stream>>>(x, Wq, Wk, Wv, Wo, xb, wqb, wkb, wvb, wob);
    qkv_gemm<<<dim3(MTOT / 128, 24), 256, 0, stream>>>(xb, wqb, wkb, wvb, qb, kb, vtb);
    attn_kernel<<<dim3(Tt / 64, NH, Bb), 256, 0, stream>>>(qb, kb, vtb, aob);
    out_gemm<<<dim3(MTOT / 128, Dm / 128), 256, 0, stream>>>(aob, wob, bo, out);
}

// Round 10
// 225.383 us; speedup vs baseline: 7.0214x; 1.0489x over previous
//
#include <hip/hip_runtime.h>
#include <math.h>

// Problem constants
constexpr int Dm   = 1024;
constexpr int NH   = 16;
constexpr int HD   = 64;
constexpr int Bb   = 2;
constexpr int Tt   = 2048;
constexpr int MTOT = Bb * Tt;   // 4096
#define EPSF 1e-6f

typedef __attribute__((ext_vector_type(8))) short short8;   // 8 x bf16
typedef __attribute__((ext_vector_type(4))) float f32x4;    // MFMA acc
typedef __attribute__((ext_vector_type(2))) float f32x2;    // packed fp32 pair

__device__ __forceinline__ ushort f2bf(float f) {
    union { float f; unsigned u; } v; v.f = f;
    unsigned r = (v.u + 0x7FFFu + ((v.u >> 16) & 1u)) >> 16;   // RNE
    return (ushort)r;
}
// half-up round (differs from RNE only on exact-0x8000 tails — negligible)
__device__ __forceinline__ ushort f2bf_hu(float f) {
    return (ushort)((__builtin_bit_cast(unsigned, f) + 0x8000u) >> 16);
}

// async global->LDS, 16B/lane. PROVEN in gemm_core; CONVICTED in attn (R4-R6
// fails, R7 bisect) — do not use outside gemm-style kernels.
__device__ __forceinline__ void gload16(const void* g, void* l) {
    __builtin_amdgcn_global_load_lds(
        (const __attribute__((address_space(1))) unsigned int*)g,
        (__attribute__((address_space(3))) unsigned int*)l,
        16, 0, 0);
}

// ---------------------------------------------------------------------------
// fp32 -> bf16 for all five tensors in one launch.
// ---------------------------------------------------------------------------
__global__ __launch_bounds__(256)
void cvt_all(const float* __restrict__ x,  const float* __restrict__ wq,
             const float* __restrict__ wk, const float* __restrict__ wv,
             const float* __restrict__ wo,
             ushort* __restrict__ xb,  ushort* __restrict__ wqb,
             ushort* __restrict__ wkb, ushort* __restrict__ wvb,
             ushort* __restrict__ wob) {
    int i = blockIdx.x * 256 + threadIdx.x;   // float4 index
    const float* src; ushort* dst; int off;
    if (i < 1048576)      { src = x;  dst = xb;  off = i; }
    else if (i < 1310720) { src = wq; dst = wqb; off = i - 1048576; }
    else if (i < 1572864) { src = wk; dst = wkb; off = i - 1310720; }
    else if (i < 1835008) { src = wv; dst = wvb; off = i - 1572864; }
    else                  { src = wo; dst = wob; off = i - 1835008; }
    const float4 v = ((const float4*)src)[off];
    ushort4 o;
    o.x = f2bf(v.x); o.y = f2bf(v.y); o.z = f2bf(v.z); o.w = f2bf(v.w);
    ((ushort4*)dst)[off] = o;
}

// ---------------------------------------------------------------------------
// 128x128x(BK=64) bf16 MFMA GEMM core (m97-style, XOR-swizzled LDS).
// PROVEN R3/R7/R8/R9. mode: 0 = plain, 1 = per-64col L2 norm (Q/K),
// 2 = V transposed per head into Vt[b,h,d,t] via packed uint2 stores.
// ---------------------------------------------------------------------------
template<bool OUTF32>
__device__ __forceinline__
void gemm_core(const ushort* __restrict__ A, const ushort* __restrict__ W,
               const float* __restrict__ bias, void* __restrict__ out,
               int m0, int n0, int N, int K, int mode) {
    __shared__ ushort As[128 * 64];
    __shared__ ushort Bs[128 * 64];
    const int tid  = threadIdx.x;
    const int wave = tid >> 6, lane = tid & 63;
    const int quad = lane >> 4, l15 = lane & 15;
    const int wr = wave >> 1, wc = wave & 1;
    const int lr = lane >> 3;
    const int sc = (lane & 7) ^ lr;

    f32x4 acc[4][4] = {};
    const ushort* Ab = A + (size_t)(m0 + lr) * K + sc * 8;
    const ushort* Wb = W + (size_t)(n0 + lr) * K + sc * 8;

    for (int k0 = 0; k0 < K; k0 += 64) {
        #pragma unroll
        for (int i = 0; i < 4; i++) {
            const int rows8 = (wave * 4 + i) * 8;
            gload16(Ab + (size_t)rows8 * K + k0, &As[rows8 * 64]);
            gload16(Wb + (size_t)rows8 * K + k0, &Bs[rows8 * 64]);
        }
        __syncthreads();
        #pragma unroll
        for (int kh = 0; kh < 2; kh++) {
            short8 af[4];
            #pragma unroll
            for (int mi = 0; mi < 4; mi++) {
                const int row = wr * 64 + mi * 16 + l15;
                af[mi] = *(const short8*)&As[row * 64 + (((kh * 4 + quad) ^ (row & 7)) * 8)];
            }
            #pragma unroll
            for (int nj = 0; nj < 4; nj++) {
                const int row = wc * 64 + nj * 16 + l15;
                const short8 bf = *(const short8*)&Bs[row * 64 + (((kh * 4 + quad) ^ (row & 7)) * 8)];
                #pragma unroll
                for (int mi = 0; mi < 4; mi++)
                    acc[mi][nj] = __builtin_amdgcn_mfma_f32_16x16x32_bf16(af[mi], bf, acc[mi][nj], 0, 0, 0);
            }
        }
        __syncthreads();
    }

    if (!OUTF32 && mode == 2) {
        #pragma unroll
        for (int mi = 0; mi < 4; mi++) {
            const int t  = m0 + wr * 64 + mi * 16 + quad * 4;
            const int bb = t >> 11, tl = t & 2047;
            #pragma unroll
            for (int nj = 0; nj < 4; nj++) {
                const int n = n0 + wc * 64 + nj * 16 + l15;
                const int hh = n >> 6, dd = n & 63;
                uint2 pk;
                pk.x = (unsigned)f2bf(acc[mi][nj][0]) | ((unsigned)f2bf(acc[mi][nj][1]) << 16);
                pk.y = (unsigned)f2bf(acc[mi][nj][2]) | ((unsigned)f2bf(acc[mi][nj][3]) << 16);
                *(uint2*)&((ushort*)out)[(size_t)((bb * NH + hh) * HD + dd) * Tt + tl] = pk;
            }
        }
        return;
    }

    #pragma unroll
    for (int mi = 0; mi < 4; mi++) {
        float inv[4] = {1.f, 1.f, 1.f, 1.f};
        if (!OUTF32 && mode == 1) {
            #pragma unroll
            for (int r = 0; r < 4; r++) {
                float ss = 0.f;
                #pragma unroll
                for (int nj = 0; nj < 4; nj++) ss += acc[mi][nj][r] * acc[mi][nj][r];
                ss += __shfl_xor(ss, 1); ss += __shfl_xor(ss, 2);
                ss += __shfl_xor(ss, 4); ss += __shfl_xor(ss, 8);
                inv[r] = 1.f / fmaxf(sqrtf(ss), EPSF);
            }
        }
        #pragma unroll
        for (int nj = 0; nj < 4; nj++)
            #pragma unroll
            for (int r = 0; r < 4; r++) {
                const int row = m0 + wr * 64 + mi * 16 + quad * 4 + r;
                const int col = n0 + wc * 64 + nj * 16 + l15;
                if (OUTF32)
                    ((float*)out)[(size_t)row * N + col] = acc[mi][nj][r] + bias[col];
                else
                    ((ushort*)out)[(size_t)row * N + col] = f2bf(acc[mi][nj][r] * inv[r]);
            }
    }
}

// Q/K: normed bf16 out; V: direct-transposed into vtb.
__global__ __launch_bounds__(256)
void qkv_gemm(const ushort* __restrict__ xb,
              const ushort* __restrict__ wq, const ushort* __restrict__ wk,
              const ushort* __restrict__ wv,
              ushort* __restrict__ qb, ushort* __restrict__ kb,
              ushort* __restrict__ vtb) {
    const int ny = blockIdx.y, sel = ny >> 3;
    const ushort* W = (sel == 0) ? wq : (sel == 1) ? wk : wv;
    ushort* out     = (sel == 0) ? qb : (sel == 1) ? kb : vtb;
    gemm_core<false>(xb, W, nullptr, out, blockIdx.x * 128, (ny & 7) * 128,
                     Dm, Dm, (sel < 2) ? 1 : 2);
}

// ---------------------------------------------------------------------------
// Output projection, 64x128 tile (grid 64x8 = 512 blocks = 2/CU vs the old
// 128x128's 256 blocks = 1/CU — co-residency for barrier overlap).
// Same staging/swizzle vocabulary as gemm_core; wave = (m-half 32) x (n-half 64).
// ---------------------------------------------------------------------------
__global__ __launch_bounds__(256)
void out_gemm(const ushort* __restrict__ A, const ushort* __restrict__ W,
              const float* __restrict__ bias, float* __restrict__ out) {
    __shared__ ushort As[64 * 64];
    __shared__ ushort Bs[128 * 64];
    const int tid  = threadIdx.x;
    const int wave = tid >> 6, lane = tid & 63;
    const int quad = lane >> 4, l15 = lane & 15;
    const int wm = wave & 1, wn = wave >> 1;
    const int lr = lane >> 3;
    const int sc = (lane & 7) ^ lr;
    const int m0 = blockIdx.x * 64, n0 = blockIdx.y * 128;
    const int K = Dm, N = Dm;

    f32x4 acc[2][4] = {};
    const ushort* Ab = A + (size_t)(m0 + lr) * K + sc * 8;
    const ushort* Wb = W + (size_t)(n0 + lr) * K + sc * 8;

    for (int k0 = 0; k0 < K; k0 += 64) {
        #pragma unroll
        for (int i = 0; i < 2; i++) {            // A: 8 groups, 2 per wave
            const int rows8 = (wave * 2 + i) * 8;
            gload16(Ab + (size_t)rows8 * K + k0, &As[rows8 * 64]);
        }
        #pragma unroll
        for (int i = 0; i < 4; i++) {            // B: 16 groups, 4 per wave
            const int rows8 = (wave * 4 + i) * 8;
            gload16(Wb + (size_t)rows8 * K + k0, &Bs[rows8 * 64]);
        }
        __syncthreads();
        #pragma unroll
        for (int kh = 0; kh < 2; kh++) {
            short8 af[2];
            #pragma unroll
            for (int mi = 0; mi < 2; mi++) {
                const int row = wm * 32 + mi * 16 + l15;
                af[mi] = *(const short8*)&As[row * 64 + (((kh * 4 + quad) ^ (row & 7)) * 8)];
            }
            #pragma unroll
            for (int nj = 0; nj < 4; nj++) {
                const int row = wn * 64 + nj * 16 + l15;
                const short8 bf = *(const short8*)&Bs[row * 64 + (((kh * 4 + quad) ^ (row & 7)) * 8)];
                #pragma unroll
                for (int mi = 0; mi < 2; mi++)
                    acc[mi][nj] = __builtin_amdgcn_mfma_f32_16x16x32_bf16(af[mi], bf, acc[mi][nj], 0, 0, 0);
            }
        }
        __syncthreads();
    }
    #pragma unroll
    for (int mi = 0; mi < 2; mi++)
        #pragma unroll
        for (int nj = 0; nj < 4; nj++)
            #pragma unroll
            for (int r = 0; r < 4; r++) {
                const int row = m0 + wm * 32 + mi * 16 + quad * 4 + r;
                const int col = n0 + wn * 64 + nj * 16 + l15;
                out[(size_t)row * N + col] = acc[mi][nj][r] + bias[col];
            }
}

// ---------------------------------------------------------------------------
// Fused angular attention, R10: R9 structure (64q tiles, double-buffered K/V
// register prefetch, XOR-swizzled unpadded LDS) with the sqrt-factored
// transform:  s = 1 - sqrt(t)*h(t),  t = clamp(1-c, 0.001, 1.999),
// h(t) = acos(1-t)/(pi*sqrt(t)) — analytic on [0,2], cubic fit exact at
// t={0,0.5,1,1.5} (s exact at c={0.999,0.5,0,-0.5}); no fabs/copysign/branch.
// ---------------------------------------------------------------------------
__global__ __launch_bounds__(256)
void attn_kernel(const ushort* __restrict__ Qb, const ushort* __restrict__ Kb,
                 const ushort* __restrict__ Vtb, ushort* __restrict__ Ob) {
    __shared__ ushort Ks[2][64 * 64];
    __shared__ ushort Vs[2][64 * 64];
    __shared__ ushort Ws[64 * 64];
    const int tid  = threadIdx.x;
    const int wave = tid >> 6, lane = tid & 63;
    const int quad = lane >> 4, l15 = lane & 15;
    const int t0 = blockIdx.x * 64, h = blockIdx.y, b = blockIdx.z;

    const size_t qrow = (size_t)(b * Tt + t0 + 16 * wave + l15) * Dm + h * HD;
    const short8 qf0 = *(const short8*)&Qb[qrow + quad * 8];
    const short8 qf1 = *(const short8*)&Qb[qrow + 32 + quad * 8];

    const size_t kbase  = (size_t)(b * Tt) * Dm + h * HD;
    const size_t vtbase = (size_t)((b * NH + h) * HD) * Tt;
    const int r0 = tid >> 3, ch0 = tid & 7;
    const ushort* kg = Kb  + kbase  + (size_t)r0 * Dm + ch0 * 8;
    const ushort* vg = Vtb + vtbase + (size_t)r0 * Tt + ch0 * 8;
    const int lsw0 = r0 * 64 + ((ch0 ^ (r0 & 7)) * 8);
    const int lsw1 = (r0 + 32) * 64 + ((ch0 ^ (r0 & 7)) * 8);

    f32x4 oacc[4] = {};
    f32x2 denp[4] = {};

    // h(t) cubic: nodes t=0,0.5,1,1.5
    const f32x2 h3 = { 0.011180f,  0.011180f};
    const f32x2 h2 = {-0.002070f, -0.002070f};
    const f32x2 h1 = { 0.040732f,  0.040732f};
    const f32x2 h0 = { 0.450158f,  0.450158f};

    // prologue: stage tile 0 into buffer 0
    short8 pk0 = *(const short8*)kg;
    short8 pk1 = *(const short8*)(kg + (size_t)32 * Dm);
    short8 pv0 = *(const short8*)vg;
    short8 pv1 = *(const short8*)(vg + (size_t)32 * Tt);
    *(short8*)&Ks[0][lsw0] = pk0;  *(short8*)&Ks[0][lsw1] = pk1;
    *(short8*)&Vs[0][lsw0] = pv0;  *(short8*)&Vs[0][lsw1] = pv1;
    __syncthreads();

    for (int i = 0; i < 32; i++) {
        const int p = i & 1;
        if (i < 31) {   // prefetch next tile into registers
            const size_t sn = (size_t)(i + 1) * 64;
            pk0 = *(const short8*)(kg + sn * Dm);
            pk1 = *(const short8*)(kg + (sn + 32) * Dm);
            pv0 = *(const short8*)(vg + sn);
            pv1 = *(const short8*)(vg + sn + (size_t)32 * Tt);
        }

        // S = Q K^T
        f32x4 sf[4] = {};
        #pragma unroll
        for (int j = 0; j < 4; j++) {
            const int row = 16 * j + l15;
            const short8 kf0 = *(const short8*)&Ks[p][row * 64 + ((quad ^ (row & 7)) * 8)];
            const short8 kf1 = *(const short8*)&Ks[p][row * 64 + (((4 + quad) ^ (row & 7)) * 8)];
            sf[j] = __builtin_amdgcn_mfma_f32_16x16x32_bf16(qf0, kf0, sf[j], 0, 0, 0);
            sf[j] = __builtin_amdgcn_mfma_f32_16x16x32_bf16(qf1, kf1, sf[j], 0, 0, 0);
        }

        // sqrt-factored angular transform, pair-packed
        #pragma unroll
        for (int r = 0; r < 4; r++) {
            f32x2 tA, tB;
            tA.x = __builtin_amdgcn_fmed3f(1.0f - sf[0][r], 0.001f, 1.999f);
            tA.y = __builtin_amdgcn_fmed3f(1.0f - sf[1][r], 0.001f, 1.999f);
            tB.x = __builtin_amdgcn_fmed3f(1.0f - sf[2][r], 0.001f, 1.999f);
            tB.y = __builtin_amdgcn_fmed3f(1.0f - sf[3][r], 0.001f, 1.999f);
            f32x2 pa = __builtin_elementwise_fma(tA, h3, h2);
            f32x2 pb = __builtin_elementwise_fma(tB, h3, h2);
            pa = __builtin_elementwise_fma(pa, tA, h1);
            pb = __builtin_elementwise_fma(pb, tB, h1);
            pa = __builtin_elementwise_fma(pa, tA, h0);
            pb = __builtin_elementwise_fma(pb, tB, h0);
            f32x2 ra, rb;
            ra.x = __builtin_amdgcn_sqrtf(tA.x); ra.y = __builtin_amdgcn_sqrtf(tA.y);
            rb.x = __builtin_amdgcn_sqrtf(tB.x); rb.y = __builtin_amdgcn_sqrtf(tB.y);
            const f32x2 one2 = {1.0f, 1.0f};
            f32x2 wa = __builtin_elementwise_fma(-ra, pa, one2);   // s = 1 - rt*h
            f32x2 wb = __builtin_elementwise_fma(-rb, pb, one2);
            wa *= wa; wa *= wa; wa *= wa; wa *= wa;                // s^16
            wb *= wb; wb *= wb; wb *= wb; wb *= wb;
            denp[r] += wa; denp[r] += wb;
            const int wrow = 16 * wave + quad * 4 + r;
            const int wb7 = wrow & 7;
            const int base = wrow * 64 + (l15 & 7);
            const int hc = l15 >> 3;
            Ws[base + (((hc)     ^ wb7) * 8)] = f2bf_hu(wa.x);
            Ws[base + (((hc + 2) ^ wb7) * 8)] = f2bf_hu(wa.y);
            Ws[base + (((hc + 4) ^ wb7) * 8)] = f2bf_hu(wb.x);
            Ws[base + (((hc + 6) ^ wb7) * 8)] = f2bf_hu(wb.y);
        }
        __syncthreads();   // A: Ws ready

        // O += W V
        const int wrow = 16 * wave + l15;
        const short8 wf0 = *(const short8*)&Ws[wrow * 64 + ((quad ^ (wrow & 7)) * 8)];
        const short8 wf1 = *(const short8*)&Ws[wrow * 64 + (((4 + quad) ^ (wrow & 7)) * 8)];
        #pragma unroll
        for (int j = 0; j < 4; j++) {
            const int vrow = 16 * j + l15;
            const short8 vf0 = *(const short8*)&Vs[p][vrow * 64 + ((quad ^ (vrow & 7)) * 8)];
            const short8 vf1 = *(const short8*)&Vs[p][vrow * 64 + (((4 + quad) ^ (vrow & 7)) * 8)];
            oacc[j] = __builtin_amdgcn_mfma_f32_16x16x32_bf16(wf0, vf0, oacc[j], 0, 0, 0);
            oacc[j] = __builtin_amdgcn_mfma_f32_16x16x32_bf16(wf1, vf1, oacc[j], 0, 0, 0);
        }
        if (i < 31) {
            *(short8*)&Ks[1 - p][lsw0] = pk0;  *(short8*)&Ks[1 - p][lsw1] = pk1;
            *(short8*)&Vs[1 - p][lsw0] = pv0;  *(short8*)&Vs[1 - p][lsw1] = pv1;
        }
        __syncthreads();   // B: staging visible; Ws/Vs reads done everywhere
    }

    // epilogue (rcp instead of IEEE divide: den >= 0.79, 1e-5 rel err fine)
    float den[4];
    #pragma unroll
    for (int r = 0; r < 4; r++) {
        float d = denp[r].x + denp[r].y;
        d += __shfl_xor(d, 1); d += __shfl_xor(d, 2);
        d += __shfl_xor(d, 4); d += __shfl_xor(d, 8);
        den[r] = __builtin_amdgcn_rcpf(d + EPSF);
    }
    const size_t obase =
        (size_t)(b * Tt + t0 + 16 * wave + quad * 4) * Dm + h * HD + l15;
    #pragma unroll
    for (int j = 0; j < 4; j++)
        #pragma unroll
        for (int r = 0; r < 4; r++)
            Ob[obase + (size_t)r * Dm + 16 * j] = f2bf(oacc[j][r] * den[r]);
}

// ---------------------------------------------------------------------------
extern "C" void kernel_launch(void* const* d_in, const int* in_sizes, int n_in,
                              void* d_out, int out_size, void* d_ws, size_t ws_size,
                              hipStream_t stream) {
    const float* x  = (const float*)d_in[0];
    const float* Wq = (const float*)d_in[1];
    const float* Wk = (const float*)d_in[2];
    const float* Wv = (const float*)d_in[3];
    const float* Wo = (const float*)d_in[4];
    const float* bo = (const float*)d_in[5];
    float* out = (float*)d_out;

    ushort* ws = (ushort*)d_ws;
    const size_t M1 = 1u << 20;
    ushort* xb  = ws;
    ushort* wqb = ws + 4 * M1;
    ushort* wkb = ws + 5 * M1;
    ushort* wvb = ws + 6 * M1;
    ushort* wob = ws + 7 * M1;
    ushort* qb  = ws + 8 * M1;
    ushort* kb  = ws + 12 * M1;
    ushort* vtb = ws + 16 * M1;
    ushort* aob = ws + 20 * M1;

    cvt_all<<<8192, 256, 0, stream>>>(x, Wq, Wk, Wv, Wo, xb, wqb, wkb, wvb, wob);
    qkv_gemm<<<dim3(MTOT / 128, 24), 256, 0, stream>>>(xb, wqb, wkb, wvb, qb, kb, vtb);
    attn_kernel<<<dim3(Tt / 64, NH, Bb), 256, 0, stream>>>(qb, kb, vtb, aob);
    out_gemm<<<dim3(MTOT / 64, Dm / 128), 256, 0, stream>>>(aob, wob, bo, out);
}